// Round 13
// baseline (1373.449 us; speedup 1.0000x reference)
//
#include <hip/hip_runtime.h>
#include <hip/hip_bf16.h>

// MambaEncoder on MI355X — v13: v10 base (best, 902us k_layers) with ONE change:
//  __launch_bounds__(512,4) (was (512,2)). The 2nd arg is waves-per-SIMD:
//  (512,2) requested only 1 block/CU -> every prior k_layer ran at 8 waves/CU
//  (Occupancy 23.7%), latency-dead. (512,4) -> 2 blocks/CU = 16 waves/CU;
//  LDS 2x64KB=128KB <= 160KB and VGPR 128/wave both permit it.
// Structure (v10): k_in_proj | k_layers (both layers, block=sequence, 512 thr
// / 8 waves, wave owns 32 cols, 7 __syncthreads/tile, exact reg scan) | k_out.

typedef __attribute__((ext_vector_type(8))) __bf16 bf16x8;
typedef __attribute__((ext_vector_type(8))) short short8;
typedef __attribute__((ext_vector_type(4))) float f32x4;
typedef __attribute__((ext_vector_type(4))) unsigned u32x4;

#define NSEQ 512
#define KSEQ 512
#define FIN 96
#define DMODEL 256
#define MTOT (NSEQ*KSEQ)

__device__ __forceinline__ unsigned short f2bf(float f){
  union { float f; unsigned u; } v; v.f = f;
  unsigned r = (v.u + 0x7FFFu + ((v.u >> 16) & 1u)) >> 16;
  return (unsigned short)r;
}
__device__ __forceinline__ float bf2f(unsigned short b){
  union { unsigned u; float f; } v; v.u = ((unsigned)b) << 16; return v.f;
}
__device__ __forceinline__ unsigned pk_bf16(float lo, float hi){
  unsigned r;
  asm("v_cvt_pk_bf16_f32 %0, %1, %2" : "=v"(r) : "v"(lo), "v"(hi));
  return r;
}
__device__ __forceinline__ float gelu_f(float x){
  return 0.5f * x * (1.0f + erff(x * 0.70710678118654752440f));
}
__device__ __forceinline__ float silu_f(float x){
  return x / (1.0f + __expf(-x));
}
__device__ __forceinline__ unsigned swzA(int row, int kbyte){   // [64][256] bf16, 512B stride
  return ((unsigned)(row*512 + kbyte)) ^ (unsigned)((row & 7) << 4);
}
__device__ __forceinline__ unsigned swzB(int n, int kbyte){     // [256][64] bf16
  return ((unsigned)(n*128 + kbyte)) ^ (unsigned)((n & 7) << 4);
}

// 8-wave col-split GEMM: acc[4][2] += A(64x256 LDS, swzA) @ W[cols c0..c0+32]^T
// B direct from global (cache-resident), 4-deep chunk prefetch ring.
__device__ __forceinline__ void gemm_w8(const unsigned short* __restrict__ wb,
                                        const char* As, f32x4 (&acc)[4][2],
                                        int lane, int c0)
{
  const int lr  = lane & 15;
  const int lk8 = (lane >> 4) * 8;
  const unsigned short* bp = wb + (size_t)(c0 + lr)*256 + lk8;   // +fc*4096 +kc*32
  bf16x8 bb[4][2];
  #pragma unroll
  for(int p = 0; p < 4; ++p)
    #pragma unroll
    for(int fc = 0; fc < 2; ++fc)
      bb[p][fc] = *(const bf16x8*)(bp + fc*4096 + p*32);
  #pragma unroll
  for(int kc = 0; kc < 8; ++kc){
    bf16x8 af[4];
    #pragma unroll
    for(int fr = 0; fr < 4; ++fr)
      af[fr] = *(const bf16x8*)(As + swzA(fr*16 + lr, kc*64 + lk8*2));
    #pragma unroll
    for(int fr = 0; fr < 4; ++fr)
      #pragma unroll
      for(int fc = 0; fc < 2; ++fc)
        acc[fr][fc] = __builtin_amdgcn_mfma_f32_16x16x32_bf16(af[fr], bb[kc&3][fc], acc[fr][fc], 0, 0, 0);
    if(kc < 4){
      #pragma unroll
      for(int fc = 0; fc < 2; ++fc)
        bb[kc&3][fc] = *(const bf16x8*)(bp + fc*4096 + (kc+4)*32);
    }
  }
}

__device__ __forceinline__ void zero_acc2(f32x4 (&acc)[4][2]){
  #pragma unroll
  for(int a=0;a<4;++a)
    #pragma unroll
    for(int b=0;b<2;++b)
      acc[a][b] = (f32x4){0.f,0.f,0.f,0.f};
}
__device__ __forceinline__ void zero_acc(f32x4 (&acc)[4][4]){
  #pragma unroll
  for(int a=0;a<4;++a)
    #pragma unroll
    for(int b=0;b<4;++b)
      acc[a][b] = (f32x4){0.f,0.f,0.f,0.f};
}

// LDS-staged GEMM (k_in_proj / k_out only, proven, 256 thr)
template<int KCH>
__device__ __forceinline__ void gemm_64x256(const unsigned short* __restrict__ wb,
                                            char* As, char* Bs,
                                            f32x4 (&acc)[4][4], int tid)
{
  const int lane = tid & 63;
  const int c0   = (tid >> 6) * 64;
  const int lr   = lane & 15;
  const int lk16 = (lane >> 4) * 16;
  #pragma unroll
  for(int kc = 0; kc < KCH; ++kc){
    __syncthreads();
    {
      const unsigned short* src = wb + (size_t)tid * (KCH*64) + kc*64;
      #pragma unroll
      for(int i = 0; i < 8; ++i){
        short8 v = *(const short8*)(src + i*8);
        *(short8*)(Bs + swzB(tid, i*16)) = v;
      }
    }
    __syncthreads();
    #pragma unroll
    for(int t2 = 0; t2 < 2; ++t2){
      bf16x8 af[4], bfr[4];
      #pragma unroll
      for(int fr = 0; fr < 4; ++fr)
        af[fr] = *(const bf16x8*)(As + swzA(fr*16 + lr, kc*128 + t2*64 + lk16));
      #pragma unroll
      for(int fc = 0; fc < 4; ++fc)
        bfr[fc] = *(const bf16x8*)(Bs + swzB(c0 + fc*16 + lr, t2*64 + lk16));
      #pragma unroll
      for(int fr = 0; fr < 4; ++fr)
        #pragma unroll
        for(int fc = 0; fc < 4; ++fc)
          acc[fr][fc] = __builtin_amdgcn_mfma_f32_16x16x32_bf16(af[fr], bfr[fc], acc[fr][fc], 0, 0, 0);
    }
  }
}

// ---------------- prep kernels ----------------
__global__ void k_cvt(const float* __restrict__ s, unsigned short* __restrict__ d, int n){
  int i = blockIdx.x*256 + threadIdx.x;
  if(i < n) d[i] = f2bf(s[i]);
}
__global__ void k_cvt_inw(const float* __restrict__ w, unsigned short* __restrict__ d){
  int i = blockIdx.x*256 + threadIdx.x;
  int n = i >> 7, f = i & 127;
  d[i] = (f < 96) ? f2bf(w[n*96 + f]) : (unsigned short)0;
}
__global__ void k_spT(const float* __restrict__ spw, unsigned short* __restrict__ d){
  int l = blockIdx.y;
  int i = blockIdx.x*256 + threadIdx.x;
  int dd = i >> 8, ss = i & 255;
  d[l*65536 + i] = f2bf(spw[l*65536 + ss*256 + dd]);
}
__global__ void k_decay(const float* __restrict__ A_log, float* __restrict__ decay){
  __shared__ float red[4];
  const int b = blockIdx.x;            // l*256 + d
  const int tid = threadIdx.x;
  float v = expf(A_log[(size_t)b*256 + tid]);
  #pragma unroll
  for(int o = 32; o >= 1; o >>= 1) v += __shfl_xor(v, o);
  if((tid & 63) == 0) red[tid >> 6] = v;
  __syncthreads();
  if(tid == 0){
    float s = red[0] + red[1] + red[2] + red[3];
    decay[b] = expf(-s * (1.f/256.f));
  }
}

// ---------------- h = gelu(LN(x @ in_w^T + in_b)) -> bf16 (proven) ----------------
__global__ __launch_bounds__(256) void k_in_proj(
    const float* __restrict__ x_g,
    const unsigned short* __restrict__ in_wb,
    const float* __restrict__ in_b,
    const float* __restrict__ ln_gv, const float* __restrict__ ln_bv,
    unsigned short* __restrict__ h_g)
{
  __shared__ char smem[65536];
  char* As = smem; char* Bs = smem + 32768;
  const int tid = threadIdx.x;
  const int m0 = blockIdx.x * 64;
  const int lane = tid & 63, c0w = (tid>>6)*64, lr = lane & 15, rb = (lane>>4)*4;
  {
    const int r = tid >> 2, cq = tid & 3;
    const float* src = x_g + (size_t)(m0 + r)*FIN + cq*24;
    unsigned short tmp[24] __attribute__((aligned(16)));
    #pragma unroll
    for(int i = 0; i < 6; ++i){
      float4 v = *(const float4*)(src + i*4);
      tmp[4*i]=f2bf(v.x); tmp[4*i+1]=f2bf(v.y); tmp[4*i+2]=f2bf(v.z); tmp[4*i+3]=f2bf(v.w);
    }
    #pragma unroll
    for(int i = 0; i < 3; ++i)
      *(short8*)(As + swzA(r, cq*48 + i*16)) = *(const short8*)(tmp + i*8);
    if(cq == 3){
      short8 z8 = {0,0,0,0,0,0,0,0};
      #pragma unroll
      for(int i = 0; i < 4; ++i)
        *(short8*)(As + swzA(r, 192 + i*16)) = z8;
    }
  }
  f32x4 acc[4][4]; zero_acc(acc);
  gemm_64x256<2>(in_wb, As, Bs, acc, tid);
  __syncthreads();
  #pragma unroll
  for(int fc = 0; fc < 4; ++fc){
    const int col = c0w + fc*16 + lr;
    const float bb = in_b[col];
    #pragma unroll
    for(int fr = 0; fr < 4; ++fr)
      #pragma unroll
      for(int rg = 0; rg < 4; ++rg){
        const int row = fr*16 + rb + rg;
        *(float*)(smem + (((unsigned)(row*1024 + col*4)) ^ ((row&7)<<4))) = acc[fr][fc][rg] + bb;
      }
  }
  __syncthreads();
  {
    const int r = tid >> 2, c0 = (tid & 3) * 64;
    float vals[64]; float sm = 0.f, sq = 0.f;
    #pragma unroll
    for(int i = 0; i < 16; ++i){
      float4 v = *(const float4*)(smem + (((unsigned)(r*1024 + (c0 + i*4)*4)) ^ ((r&7)<<4)));
      vals[4*i]=v.x; vals[4*i+1]=v.y; vals[4*i+2]=v.z; vals[4*i+3]=v.w;
    }
    #pragma unroll
    for(int i = 0; i < 64; ++i){ sm += vals[i]; sq += vals[i]*vals[i]; }
    sm += __shfl_xor(sm, 1); sm += __shfl_xor(sm, 2);
    sq += __shfl_xor(sq, 1); sq += __shfl_xor(sq, 2);
    const float mu = sm * (1.f/256.f);
    const float rstd = rsqrtf(sq * (1.f/256.f) - mu*mu + 1e-5f);
    unsigned short* dst = h_g + (size_t)(m0 + r)*DMODEL + c0;
    #pragma unroll
    for(int i = 0; i < 8; ++i){
      float g[8];
      #pragma unroll
      for(int j = 0; j < 8; ++j){
        const int c = c0 + i*8 + j;
        g[j] = gelu_f((vals[i*8+j]-mu)*rstd*ln_gv[c] + ln_bv[c]);
      }
      u32x4 o;
      o[0] = pk_bf16(g[0],g[1]); o[1] = pk_bf16(g[2],g[3]);
      o[2] = pk_bf16(g[4],g[5]); o[3] = pk_bf16(g[6],g[7]);
      *(u32x4*)(dst + i*8) = o;
    }
  }
}

// ---------------- BOTH layers: block = sequence, 512 thr / 8 waves ----------------
__global__ __launch_bounds__(512,4) void k_layers(
    unsigned short* __restrict__ h_g,
    const unsigned short* __restrict__ gate_w0,
    const unsigned short* __restrict__ sp_w0,
    const unsigned short* __restrict__ spT_w0,
    const unsigned short* __restrict__ op_w0,
    const float* __restrict__ ln_g0, const float* __restrict__ ln_b0,
    const float* __restrict__ gate_b0, const float* __restrict__ sp_b0,
    const float* __restrict__ decay0, const float* __restrict__ D0,
    const float* __restrict__ op_b0)
{
  __shared__ char As[32768];
  __shared__ char Ss[32768];
  const int tid = threadIdx.x;
  const int n = blockIdx.x;
  const int lane = tid & 63;
  const int c0w = (tid >> 6) * 32;            // wave -> 32 output cols
  const int lr = lane & 15, rb = (lane>>4)*4;
  const int rA = tid >> 3, cAh = (tid & 7) * 32;   // LN: 8 thr/row
  float st = 0.f;                              // scan state across layers

  #pragma unroll 1
  for(int l = 0; l < 2; ++l){
    const unsigned short* gw  = gate_w0 + l*65536;
    const unsigned short* spw = sp_w0   + l*65536;
    const unsigned short* spT = spT_w0  + l*65536;
    const unsigned short* opw = op_w0   + l*65536;
    const float* lg  = ln_g0   + l*256;
    const float* lb  = ln_b0   + l*256;
    const float* gb_ = gate_b0 + l*256;
    const float* sb_ = sp_b0   + l*256;
    const float* Dv_ = D0      + l*256;
    const float* ob_ = op_b0   + l*256;
    const float dc = decay0[l*256 + (tid & 255)];

    #pragma unroll 1
    for(int kb = 0; kb < 8; ++kb){
      const int m0 = n*KSEQ + kb*64;
      // ---- Phase A: LN(h) -> z bf16 in As (8 thr/row) ----
      {
        const unsigned short* src = h_g + (size_t)(m0 + rA)*DMODEL + cAh;
        short8 hv[4];
        #pragma unroll
        for(int i = 0; i < 4; ++i) hv[i] = *(const short8*)(src + i*8);
        float sm = 0.f, sq = 0.f;
        #pragma unroll
        for(int i = 0; i < 4; ++i)
          #pragma unroll
          for(int j = 0; j < 8; ++j){
            float v = bf2f((unsigned short)hv[i][j]); sm += v; sq += v*v;
          }
        sm += __shfl_xor(sm, 1); sm += __shfl_xor(sm, 2); sm += __shfl_xor(sm, 4);
        sq += __shfl_xor(sq, 1); sq += __shfl_xor(sq, 2); sq += __shfl_xor(sq, 4);
        const float mu = sm * (1.f/256.f);
        const float rstd = rsqrtf(sq * (1.f/256.f) - mu*mu + 1e-5f);
        #pragma unroll
        for(int i = 0; i < 4; ++i){
          float z[8];
          #pragma unroll
          for(int j = 0; j < 8; ++j){
            const int c = cAh + i*8 + j;
            z[j] = (bf2f((unsigned short)hv[i][j])-mu)*rstd*lg[c] + lb[c];
          }
          u32x4 zz;
          zz[0] = pk_bf16(z[0],z[1]); zz[1] = pk_bf16(z[2],z[3]);
          zz[2] = pk_bf16(z[4],z[5]); zz[3] = pk_bf16(z[6],z[7]);
          *(u32x4*)(As + swzA(rA, cAh*2 + i*16)) = zz;
        }
      }
      __syncthreads();                                 // S1
      f32x4 acc[4][2]; zero_acc2(acc);
      gemm_w8(gw, As, acc, lane, c0w);
      // xg = silu(acc+gb) -> Ss
      #pragma unroll
      for(int fc = 0; fc < 2; ++fc){
        const int col = c0w + fc*16 + lr;
        const float gb = gb_[col];
        #pragma unroll
        for(int fr = 0; fr < 4; ++fr){
          const int row = fr*16 + rb;
          float v0 = silu_f(acc[fr][fc][0] + gb), v1 = silu_f(acc[fr][fc][1] + gb);
          float v2 = silu_f(acc[fr][fc][2] + gb), v3 = silu_f(acc[fr][fc][3] + gb);
          unsigned p0 = pk_bf16(v0, v1), p1 = pk_bf16(v2, v3);
          *(unsigned short*)(Ss + swzA(row+0, col*2)) = (unsigned short)p0;
          *(unsigned short*)(Ss + swzA(row+1, col*2)) = (unsigned short)(p0 >> 16);
          *(unsigned short*)(Ss + swzA(row+2, col*2)) = (unsigned short)p1;
          *(unsigned short*)(Ss + swzA(row+3, col*2)) = (unsigned short)(p1 >> 16);
        }
      }
      __syncthreads();                                 // S2
      zero_acc2(acc);
      gemm_w8(spw, Ss, acc, lane, c0w);
      // s = acc + sp_b -> As
      #pragma unroll
      for(int fc = 0; fc < 2; ++fc){
        const int col = c0w + fc*16 + lr;
        const float sb = sb_[col];
        #pragma unroll
        for(int fr = 0; fr < 4; ++fr){
          const int row = fr*16 + rb;
          unsigned p0 = pk_bf16(acc[fr][fc][0] + sb, acc[fr][fc][1] + sb);
          unsigned p1 = pk_bf16(acc[fr][fc][2] + sb, acc[fr][fc][3] + sb);
          *(unsigned short*)(As + swzA(row+0, col*2)) = (unsigned short)p0;
          *(unsigned short*)(As + swzA(row+1, col*2)) = (unsigned short)(p0 >> 16);
          *(unsigned short*)(As + swzA(row+2, col*2)) = (unsigned short)p1;
          *(unsigned short*)(As + swzA(row+3, col*2)) = (unsigned short)(p1 >> 16);
        }
      }
      __syncthreads();                                 // S3
      // ---- scan (thread = channel, tid<256), chunked 16 ----
      if(tid < 256){
        #pragma unroll
        for(int c4 = 0; c4 < 4; ++c4){
          const int base = c4*16;
          float v[16];
          #pragma unroll
          for(int j = 0; j < 16; ++j)
            v[j] = bf2f(*(const unsigned short*)(As + swzA(base+j, tid*2)));
          #pragma unroll
          for(int j = 0; j < 16; ++j){ st = st*dc + v[j]; v[j] = st; }
          #pragma unroll
          for(int j = 0; j < 8; ++j){
            unsigned p = pk_bf16(v[2*j], v[2*j+1]);
            *(unsigned short*)(As + swzA(base+2*j,   tid*2)) = (unsigned short)p;
            *(unsigned short*)(As + swzA(base+2*j+1, tid*2)) = (unsigned short)(p >> 16);
          }
        }
      }
      __syncthreads();                                 // S4
      zero_acc2(acc);
      gemm_w8(spT, As, acc, lane, c0w);                // y1 = states@sp_w
      __syncthreads();                                 // S5
      // y = acc + D*xg (xg from Ss) -> As
      #pragma unroll
      for(int fc = 0; fc < 2; ++fc){
        const int col = c0w + fc*16 + lr;
        const float Dv = Dv_[col];
        #pragma unroll
        for(int fr = 0; fr < 4; ++fr){
          const int row = fr*16 + rb;
          float y0 = acc[fr][fc][0] + Dv*bf2f(*(const unsigned short*)(Ss + swzA(row+0, col*2)));
          float y1 = acc[fr][fc][1] + Dv*bf2f(*(const unsigned short*)(Ss + swzA(row+1, col*2)));
          float y2 = acc[fr][fc][2] + Dv*bf2f(*(const unsigned short*)(Ss + swzA(row+2, col*2)));
          float y3 = acc[fr][fc][3] + Dv*bf2f(*(const unsigned short*)(Ss + swzA(row+3, col*2)));
          unsigned p0 = pk_bf16(y0, y1), p1 = pk_bf16(y2, y3);
          *(unsigned short*)(As + swzA(row+0, col*2)) = (unsigned short)p0;
          *(unsigned short*)(As + swzA(row+1, col*2)) = (unsigned short)(p0 >> 16);
          *(unsigned short*)(As + swzA(row+2, col*2)) = (unsigned short)p1;
          *(unsigned short*)(As + swzA(row+3, col*2)) = (unsigned short)(p1 >> 16);
        }
      }
      __syncthreads();                                 // S6
      zero_acc2(acc);
      gemm_w8(opw, As, acc, lane, c0w);                // @op^T
      // acc + op_b -> Ss
      #pragma unroll
      for(int fc = 0; fc < 2; ++fc){
        const int col = c0w + fc*16 + lr;
        const float ob = ob_[col];
        #pragma unroll
        for(int fr = 0; fr < 4; ++fr){
          const int row = fr*16 + rb;
          unsigned p0 = pk_bf16(acc[fr][fc][0] + ob, acc[fr][fc][1] + ob);
          unsigned p1 = pk_bf16(acc[fr][fc][2] + ob, acc[fr][fc][3] + ob);
          *(unsigned short*)(Ss + swzA(row+0, col*2)) = (unsigned short)p0;
          *(unsigned short*)(Ss + swzA(row+1, col*2)) = (unsigned short)(p0 >> 16);
          *(unsigned short*)(Ss + swzA(row+2, col*2)) = (unsigned short)p1;
          *(unsigned short*)(Ss + swzA(row+3, col*2)) = (unsigned short)(p1 >> 16);
        }
      }
      __syncthreads();                                 // S7
      // h += (y@op^T + op_b), coalesced RMW from Ss (4 x 16B/thread)
      {
        char* dst = (char*)(h_g + (size_t)m0*DMODEL);
        #pragma unroll
        for(int i = 0; i < 4; ++i){
          const unsigned flat = (unsigned)(i*8192 + tid*16);
          const unsigned row = flat >> 9;
          short8 a = *(const short8*)(Ss + (flat ^ ((row & 7u) << 4)));
          short8 hv = *(const short8*)(dst + flat);
          u32x4 o;
          #pragma unroll
          for(int j = 0; j < 4; ++j){
            float s0 = bf2f((unsigned short)a[2*j])   + bf2f((unsigned short)hv[2*j]);
            float s1 = bf2f((unsigned short)a[2*j+1]) + bf2f((unsigned short)hv[2*j+1]);
            o[j] = pk_bf16(s0, s1);
          }
          *(u32x4*)(dst + flat) = o;
        }
      }
      // next Phase A writes As only after S7 (As reads done); Ss fenced by S1
    }
  }
}

// ---------------- out = gelu(LN(h[:,511,:] @ out_w^T + out_b)) (proven) ----------------
__global__ __launch_bounds__(256) void k_out(
    const unsigned short* __restrict__ h_g,
    const unsigned short* __restrict__ out_wb,
    const float* __restrict__ out_bv,
    const float* __restrict__ ln_gv, const float* __restrict__ ln_bv,
    float* __restrict__ out_g)
{
  __shared__ char smem[65536];
  char* As = smem; char* Bs = smem + 32768;
  const int tid = threadIdx.x;
  const int r0 = blockIdx.x * 64;
  const int lane = tid & 63, c0w = (tid>>6)*64, lr = lane & 15, rb = (lane>>4)*4;
  {
    const int r = tid >> 2, c0 = (tid & 3) * 64;
    const unsigned short* src = h_g + ((size_t)(r0 + r)*KSEQ + (KSEQ-1))*DMODEL + c0;
    #pragma unroll
    for(int i = 0; i < 8; ++i){
      short8 v = *(const short8*)(src + i*8);
      *(short8*)(As + swzA(r, c0*2 + i*16)) = v;
    }
  }
  f32x4 acc[4][4]; zero_acc(acc);
  gemm_64x256<4>(out_wb, As, Bs, acc, tid);
  __syncthreads();
  #pragma unroll
  for(int fc = 0; fc < 4; ++fc){
    const int col = c0w + fc*16 + lr;
    const float bb = out_bv[col];
    #pragma unroll
    for(int fr = 0; fr < 4; ++fr)
      #pragma unroll
      for(int rg = 0; rg < 4; ++rg){
        const int row = fr*16 + rb + rg;
        *(float*)(smem + (((unsigned)(row*1024 + col*4)) ^ ((row&7)<<4))) = acc[fr][fc][rg] + bb;
      }
  }
  __syncthreads();
  {
    const int r = tid >> 2, c0 = (tid & 3) * 64;
    float vals[64]; float sm = 0.f, sq = 0.f;
    #pragma unroll
    for(int i = 0; i < 16; ++i){
      float4 v = *(const float4*)(smem + (((unsigned)(r*1024 + (c0 + i*4)*4)) ^ ((r&7)<<4)));
      vals[4*i]=v.x; vals[4*i+1]=v.y; vals[4*i+2]=v.z; vals[4*i+3]=v.w;
    }
    #pragma unroll
    for(int i = 0; i < 64; ++i){ sm += vals[i]; sq += vals[i]*vals[i]; }
    sm += __shfl_xor(sm, 1); sm += __shfl_xor(sm, 2);
    sq += __shfl_xor(sq, 1); sq += __shfl_xor(sq, 2);
    const float mu = sm * (1.f/256.f);
    const float rstd = rsqrtf(sq * (1.f/256.f) - mu*mu + 1e-5f);
    float* dst = out_g + (size_t)(r0 + r)*DMODEL + c0;
    #pragma unroll
    for(int i = 0; i < 16; ++i){
      float4 o;
      o.x = gelu_f((vals[4*i+0]-mu)*rstd*ln_gv[c0+i*4+0] + ln_bv[c0+i*4+0]);
      o.y = gelu_f((vals[4*i+1]-mu)*rstd*ln_gv[c0+i*4+1] + ln_bv[c0+i*4+1]);
      o.z = gelu_f((vals[4*i+2]-mu)*rstd*ln_gv[c0+i*4+2] + ln_bv[c0+i*4+2]);
      o.w = gelu_f((vals[4*i+3]-mu)*rstd*ln_gv[c0+i*4+3] + ln_bv[c0+i*4+3]);
      *(float4*)(dst + i*4) = o;
    }
  }
}

extern "C" void kernel_launch(void* const* d_in, const int* in_sizes, int n_in,
                              void* d_out, int out_size, void* d_ws, size_t ws_size,
                              hipStream_t stream) {
  (void)in_sizes; (void)n_in; (void)out_size; (void)ws_size;
  const float* x        = (const float*)d_in[0];
  const float* in_w     = (const float*)d_in[1];
  const float* in_b     = (const float*)d_in[2];
  const float* in_ln_g  = (const float*)d_in[3];
  const float* in_ln_b  = (const float*)d_in[4];
  const float* ln_g     = (const float*)d_in[5];
  const float* ln_b     = (const float*)d_in[6];
  const float* gate_w   = (const float*)d_in[7];
  const float* gate_b   = (const float*)d_in[8];
  const float* sp_w     = (const float*)d_in[9];
  const float* sp_b     = (const float*)d_in[10];
  const float* op_w     = (const float*)d_in[11];
  const float* op_b     = (const float*)d_in[12];
  const float* A_log    = (const float*)d_in[13];
  const float* Dp       = (const float*)d_in[14];
  const float* out_w    = (const float*)d_in[15];
  const float* out_b    = (const float*)d_in[16];
  const float* out_ln_g = (const float*)d_in[17];
  const float* out_ln_b = (const float*)d_in[18];

  char* ws = (char*)d_ws;
  // ~133.7 MiB workspace (proven budget)
  unsigned short* h_g       = (unsigned short*)(ws + 0);           // 128 MiB
  float*          decay     = (float*)(ws + 134217728);            // 2 KiB
  unsigned short* wbase     = (unsigned short*)(ws + 134219776);   // ~1.2 MiB
  unsigned short* in_wb  = wbase;               // 32768
  unsigned short* gate_wb= in_wb  + 32768;      // 2*65536
  unsigned short* sp_wb  = gate_wb+ 131072;
  unsigned short* sp_wTb = sp_wb  + 131072;
  unsigned short* op_wb  = sp_wTb + 131072;
  unsigned short* out_wb = op_wb  + 131072;     // 65536

  // prep
  k_cvt_inw<<<128, 256, 0, stream>>>(in_w, in_wb);
  k_cvt<<<512, 256, 0, stream>>>(gate_w, gate_wb, 131072);
  k_cvt<<<512, 256, 0, stream>>>(sp_w,   sp_wb,   131072);
  k_cvt<<<512, 256, 0, stream>>>(op_w,   op_wb,   131072);
  k_cvt<<<256, 256, 0, stream>>>(out_w,  out_wb,  65536);
  k_spT<<<dim3(256,2), 256, 0, stream>>>(sp_w, sp_wTb);
  k_decay<<<512, 256, 0, stream>>>(A_log, decay);

  // pipeline
  k_in_proj<<<MTOT/64, 256, 0, stream>>>(x, in_wb, in_b, in_ln_g, in_ln_b, h_g);
  k_layers<<<NSEQ, 512, 0, stream>>>(h_g, gate_wb, sp_wb, sp_wTb, op_wb,
      ln_g, ln_b, gate_b, sp_b, decay, Dp, op_b);
  k_out<<<NSEQ/64, 256, 0, stream>>>(h_g, out_wb, out_b, out_ln_g, out_ln_b, (float*)d_out);
}

// Round 14
// 1346.156 us; speedup vs baseline: 1.0203x; 1.0203x over previous
//
#include <hip/hip_runtime.h>
#include <hip/hip_bf16.h>

// MambaEncoder on MI355X — v14: v10 structure + (512,4) occupancy + REGISTER DIET.
// v13 lesson: unified VGPR pool ~512/SIMD; waves-per-eu=4 -> <=128 total/wave
// (64 arch + 64 acc). v13 spilled (~50 regs -> 2.3GB scratch FETCH). v14 diets
// gemm_w8 to fit: fr-outer loop with ONE live af fragment (4 regs, was 16) and
// 2-deep bb ring (16 regs, was 32). GEMM-phase arch ~30 + acc 32 in AGPR.
// Structure: k_in_proj | k_layers (both layers, block=sequence, 512thr/8 waves,
// wave owns 32 cols, 7 barriers/tile, exact reg scan) | k_out. ws ~133.7MiB.

typedef __attribute__((ext_vector_type(8))) __bf16 bf16x8;
typedef __attribute__((ext_vector_type(8))) short short8;
typedef __attribute__((ext_vector_type(4))) float f32x4;
typedef __attribute__((ext_vector_type(4))) unsigned u32x4;

#define NSEQ 512
#define KSEQ 512
#define FIN 96
#define DMODEL 256
#define MTOT (NSEQ*KSEQ)

__device__ __forceinline__ unsigned short f2bf(float f){
  union { float f; unsigned u; } v; v.f = f;
  unsigned r = (v.u + 0x7FFFu + ((v.u >> 16) & 1u)) >> 16;
  return (unsigned short)r;
}
__device__ __forceinline__ float bf2f(unsigned short b){
  union { unsigned u; float f; } v; v.u = ((unsigned)b) << 16; return v.f;
}
__device__ __forceinline__ unsigned pk_bf16(float lo, float hi){
  unsigned r;
  asm("v_cvt_pk_bf16_f32 %0, %1, %2" : "=v"(r) : "v"(lo), "v"(hi));
  return r;
}
__device__ __forceinline__ float gelu_f(float x){
  return 0.5f * x * (1.0f + erff(x * 0.70710678118654752440f));
}
__device__ __forceinline__ float silu_f(float x){
  return x / (1.0f + __expf(-x));
}
__device__ __forceinline__ unsigned swzA(int row, int kbyte){   // [64][256] bf16, 512B stride
  return ((unsigned)(row*512 + kbyte)) ^ (unsigned)((row & 7) << 4);
}
__device__ __forceinline__ unsigned swzB(int n, int kbyte){     // [256][64] bf16
  return ((unsigned)(n*128 + kbyte)) ^ (unsigned)((n & 7) << 4);
}

// 8-wave col-split GEMM, register-dieted: acc[4][2] += A(64x256 LDS) @ W[32 cols]^T.
// fr-outer: one af fragment live (4 regs); 2-deep bb ring (16 regs).
__device__ __forceinline__ void gemm_w8(const unsigned short* __restrict__ wb,
                                        const char* As, f32x4 (&acc)[4][2],
                                        int lane, int c0)
{
  const int lr  = lane & 15;
  const int lk8 = (lane >> 4) * 8;
  const unsigned short* bp = wb + (size_t)(c0 + lr)*256 + lk8;   // +fc*4096 +kc*32
  bf16x8 bb[2][2];
  #pragma unroll
  for(int p = 0; p < 2; ++p)
    #pragma unroll
    for(int fc = 0; fc < 2; ++fc)
      bb[p][fc] = *(const bf16x8*)(bp + fc*4096 + p*32);
  #pragma unroll
  for(int kc = 0; kc < 8; ++kc){
    #pragma unroll
    for(int fr = 0; fr < 4; ++fr){
      bf16x8 af = *(const bf16x8*)(As + swzA(fr*16 + lr, kc*64 + lk8*2));
      acc[fr][0] = __builtin_amdgcn_mfma_f32_16x16x32_bf16(af, bb[kc&1][0], acc[fr][0], 0, 0, 0);
      acc[fr][1] = __builtin_amdgcn_mfma_f32_16x16x32_bf16(af, bb[kc&1][1], acc[fr][1], 0, 0, 0);
    }
    if(kc < 6){
      #pragma unroll
      for(int fc = 0; fc < 2; ++fc)
        bb[kc&1][fc] = *(const bf16x8*)(bp + fc*4096 + (kc+2)*32);
    }
  }
}

__device__ __forceinline__ void zero_acc2(f32x4 (&acc)[4][2]){
  #pragma unroll
  for(int a=0;a<4;++a)
    #pragma unroll
    for(int b=0;b<2;++b)
      acc[a][b] = (f32x4){0.f,0.f,0.f,0.f};
}
__device__ __forceinline__ void zero_acc(f32x4 (&acc)[4][4]){
  #pragma unroll
  for(int a=0;a<4;++a)
    #pragma unroll
    for(int b=0;b<4;++b)
      acc[a][b] = (f32x4){0.f,0.f,0.f,0.f};
}

// LDS-staged GEMM (k_in_proj / k_out only, proven, 256 thr)
template<int KCH>
__device__ __forceinline__ void gemm_64x256(const unsigned short* __restrict__ wb,
                                            char* As, char* Bs,
                                            f32x4 (&acc)[4][4], int tid)
{
  const int lane = tid & 63;
  const int c0   = (tid >> 6) * 64;
  const int lr   = lane & 15;
  const int lk16 = (lane >> 4) * 16;
  #pragma unroll
  for(int kc = 0; kc < KCH; ++kc){
    __syncthreads();
    {
      const unsigned short* src = wb + (size_t)tid * (KCH*64) + kc*64;
      #pragma unroll
      for(int i = 0; i < 8; ++i){
        short8 v = *(const short8*)(src + i*8);
        *(short8*)(Bs + swzB(tid, i*16)) = v;
      }
    }
    __syncthreads();
    #pragma unroll
    for(int t2 = 0; t2 < 2; ++t2){
      bf16x8 af[4], bfr[4];
      #pragma unroll
      for(int fr = 0; fr < 4; ++fr)
        af[fr] = *(const bf16x8*)(As + swzA(fr*16 + lr, kc*128 + t2*64 + lk16));
      #pragma unroll
      for(int fc = 0; fc < 4; ++fc)
        bfr[fc] = *(const bf16x8*)(Bs + swzB(c0 + fc*16 + lr, t2*64 + lk16));
      #pragma unroll
      for(int fr = 0; fr < 4; ++fr)
        #pragma unroll
        for(int fc = 0; fc < 4; ++fc)
          acc[fr][fc] = __builtin_amdgcn_mfma_f32_16x16x32_bf16(af[fr], bfr[fc], acc[fr][fc], 0, 0, 0);
    }
  }
}

// ---------------- prep kernels ----------------
__global__ void k_cvt(const float* __restrict__ s, unsigned short* __restrict__ d, int n){
  int i = blockIdx.x*256 + threadIdx.x;
  if(i < n) d[i] = f2bf(s[i]);
}
__global__ void k_cvt_inw(const float* __restrict__ w, unsigned short* __restrict__ d){
  int i = blockIdx.x*256 + threadIdx.x;
  int n = i >> 7, f = i & 127;
  d[i] = (f < 96) ? f2bf(w[n*96 + f]) : (unsigned short)0;
}
__global__ void k_spT(const float* __restrict__ spw, unsigned short* __restrict__ d){
  int l = blockIdx.y;
  int i = blockIdx.x*256 + threadIdx.x;
  int dd = i >> 8, ss = i & 255;
  d[l*65536 + i] = f2bf(spw[l*65536 + ss*256 + dd]);
}
__global__ void k_decay(const float* __restrict__ A_log, float* __restrict__ decay){
  __shared__ float red[4];
  const int b = blockIdx.x;            // l*256 + d
  const int tid = threadIdx.x;
  float v = expf(A_log[(size_t)b*256 + tid]);
  #pragma unroll
  for(int o = 32; o >= 1; o >>= 1) v += __shfl_xor(v, o);
  if((tid & 63) == 0) red[tid >> 6] = v;
  __syncthreads();
  if(tid == 0){
    float s = red[0] + red[1] + red[2] + red[3];
    decay[b] = expf(-s * (1.f/256.f));
  }
}

// ---------------- h = gelu(LN(x @ in_w^T + in_b)) -> bf16 (proven) ----------------
__global__ __launch_bounds__(256) void k_in_proj(
    const float* __restrict__ x_g,
    const unsigned short* __restrict__ in_wb,
    const float* __restrict__ in_b,
    const float* __restrict__ ln_gv, const float* __restrict__ ln_bv,
    unsigned short* __restrict__ h_g)
{
  __shared__ char smem[65536];
  char* As = smem; char* Bs = smem + 32768;
  const int tid = threadIdx.x;
  const int m0 = blockIdx.x * 64;
  const int lane = tid & 63, c0w = (tid>>6)*64, lr = lane & 15, rb = (lane>>4)*4;
  {
    const int r = tid >> 2, cq = tid & 3;
    const float* src = x_g + (size_t)(m0 + r)*FIN + cq*24;
    unsigned short tmp[24] __attribute__((aligned(16)));
    #pragma unroll
    for(int i = 0; i < 6; ++i){
      float4 v = *(const float4*)(src + i*4);
      tmp[4*i]=f2bf(v.x); tmp[4*i+1]=f2bf(v.y); tmp[4*i+2]=f2bf(v.z); tmp[4*i+3]=f2bf(v.w);
    }
    #pragma unroll
    for(int i = 0; i < 3; ++i)
      *(short8*)(As + swzA(r, cq*48 + i*16)) = *(const short8*)(tmp + i*8);
    if(cq == 3){
      short8 z8 = {0,0,0,0,0,0,0,0};
      #pragma unroll
      for(int i = 0; i < 4; ++i)
        *(short8*)(As + swzA(r, 192 + i*16)) = z8;
    }
  }
  f32x4 acc[4][4]; zero_acc(acc);
  gemm_64x256<2>(in_wb, As, Bs, acc, tid);
  __syncthreads();
  #pragma unroll
  for(int fc = 0; fc < 4; ++fc){
    const int col = c0w + fc*16 + lr;
    const float bb = in_b[col];
    #pragma unroll
    for(int fr = 0; fr < 4; ++fr)
      #pragma unroll
      for(int rg = 0; rg < 4; ++rg){
        const int row = fr*16 + rb + rg;
        *(float*)(smem + (((unsigned)(row*1024 + col*4)) ^ ((row&7)<<4))) = acc[fr][fc][rg] + bb;
      }
  }
  __syncthreads();
  {
    const int r = tid >> 2, c0 = (tid & 3) * 64;
    float vals[64]; float sm = 0.f, sq = 0.f;
    #pragma unroll
    for(int i = 0; i < 16; ++i){
      float4 v = *(const float4*)(smem + (((unsigned)(r*1024 + (c0 + i*4)*4)) ^ ((r&7)<<4)));
      vals[4*i]=v.x; vals[4*i+1]=v.y; vals[4*i+2]=v.z; vals[4*i+3]=v.w;
    }
    #pragma unroll
    for(int i = 0; i < 64; ++i){ sm += vals[i]; sq += vals[i]*vals[i]; }
    sm += __shfl_xor(sm, 1); sm += __shfl_xor(sm, 2);
    sq += __shfl_xor(sq, 1); sq += __shfl_xor(sq, 2);
    const float mu = sm * (1.f/256.f);
    const float rstd = rsqrtf(sq * (1.f/256.f) - mu*mu + 1e-5f);
    unsigned short* dst = h_g + (size_t)(m0 + r)*DMODEL + c0;
    #pragma unroll
    for(int i = 0; i < 8; ++i){
      float g[8];
      #pragma unroll
      for(int j = 0; j < 8; ++j){
        const int c = c0 + i*8 + j;
        g[j] = gelu_f((vals[i*8+j]-mu)*rstd*ln_gv[c] + ln_bv[c]);
      }
      u32x4 o;
      o[0] = pk_bf16(g[0],g[1]); o[1] = pk_bf16(g[2],g[3]);
      o[2] = pk_bf16(g[4],g[5]); o[3] = pk_bf16(g[6],g[7]);
      *(u32x4*)(dst + i*8) = o;
    }
  }
}

// ---------------- BOTH layers: block = sequence, 512 thr / 8 waves ----------------
__global__ __launch_bounds__(512,4) void k_layers(
    unsigned short* __restrict__ h_g,
    const unsigned short* __restrict__ gate_w0,
    const unsigned short* __restrict__ sp_w0,
    const unsigned short* __restrict__ spT_w0,
    const unsigned short* __restrict__ op_w0,
    const float* __restrict__ ln_g0, const float* __restrict__ ln_b0,
    const float* __restrict__ gate_b0, const float* __restrict__ sp_b0,
    const float* __restrict__ decay0, const float* __restrict__ D0,
    const float* __restrict__ op_b0)
{
  __shared__ char As[32768];
  __shared__ char Ss[32768];
  const int tid = threadIdx.x;
  const int n = blockIdx.x;
  const int lane = tid & 63;
  const int c0w = (tid >> 6) * 32;            // wave -> 32 output cols
  const int lr = lane & 15, rb = (lane>>4)*4;
  const int rA = tid >> 3, cAh = (tid & 7) * 32;   // LN: 8 thr/row
  float st = 0.f;                              // scan state across layers

  #pragma unroll 1
  for(int l = 0; l < 2; ++l){
    const unsigned short* gw  = gate_w0 + l*65536;
    const unsigned short* spw = sp_w0   + l*65536;
    const unsigned short* spT = spT_w0  + l*65536;
    const unsigned short* opw = op_w0   + l*65536;
    const float* lg  = ln_g0   + l*256;
    const float* lb  = ln_b0   + l*256;
    const float* gb_ = gate_b0 + l*256;
    const float* sb_ = sp_b0   + l*256;
    const float* Dv_ = D0      + l*256;
    const float* ob_ = op_b0   + l*256;
    const float dc = decay0[l*256 + (tid & 255)];

    #pragma unroll 1
    for(int kb = 0; kb < 8; ++kb){
      const int m0 = n*KSEQ + kb*64;
      // ---- Phase A: LN(h) -> z bf16 in As (8 thr/row) ----
      {
        const unsigned short* src = h_g + (size_t)(m0 + rA)*DMODEL + cAh;
        short8 hv[4];
        #pragma unroll
        for(int i = 0; i < 4; ++i) hv[i] = *(const short8*)(src + i*8);
        float sm = 0.f, sq = 0.f;
        #pragma unroll
        for(int i = 0; i < 4; ++i)
          #pragma unroll
          for(int j = 0; j < 8; ++j){
            float v = bf2f((unsigned short)hv[i][j]); sm += v; sq += v*v;
          }
        sm += __shfl_xor(sm, 1); sm += __shfl_xor(sm, 2); sm += __shfl_xor(sm, 4);
        sq += __shfl_xor(sq, 1); sq += __shfl_xor(sq, 2); sq += __shfl_xor(sq, 4);
        const float mu = sm * (1.f/256.f);
        const float rstd = rsqrtf(sq * (1.f/256.f) - mu*mu + 1e-5f);
        #pragma unroll
        for(int i = 0; i < 4; ++i){
          float z[8];
          #pragma unroll
          for(int j = 0; j < 8; ++j){
            const int c = cAh + i*8 + j;
            z[j] = (bf2f((unsigned short)hv[i][j])-mu)*rstd*lg[c] + lb[c];
          }
          u32x4 zz;
          zz[0] = pk_bf16(z[0],z[1]); zz[1] = pk_bf16(z[2],z[3]);
          zz[2] = pk_bf16(z[4],z[5]); zz[3] = pk_bf16(z[6],z[7]);
          *(u32x4*)(As + swzA(rA, cAh*2 + i*16)) = zz;
        }
      }
      __syncthreads();                                 // S1
      f32x4 acc[4][2]; zero_acc2(acc);
      gemm_w8(gw, As, acc, lane, c0w);
      // xg = silu(acc+gb) -> Ss
      #pragma unroll
      for(int fc = 0; fc < 2; ++fc){
        const int col = c0w + fc*16 + lr;
        const float gb = gb_[col];
        #pragma unroll
        for(int fr = 0; fr < 4; ++fr){
          const int row = fr*16 + rb;
          float v0 = silu_f(acc[fr][fc][0] + gb), v1 = silu_f(acc[fr][fc][1] + gb);
          float v2 = silu_f(acc[fr][fc][2] + gb), v3 = silu_f(acc[fr][fc][3] + gb);
          unsigned p0 = pk_bf16(v0, v1), p1 = pk_bf16(v2, v3);
          *(unsigned short*)(Ss + swzA(row+0, col*2)) = (unsigned short)p0;
          *(unsigned short*)(Ss + swzA(row+1, col*2)) = (unsigned short)(p0 >> 16);
          *(unsigned short*)(Ss + swzA(row+2, col*2)) = (unsigned short)p1;
          *(unsigned short*)(Ss + swzA(row+3, col*2)) = (unsigned short)(p1 >> 16);
        }
      }
      __syncthreads();                                 // S2
      zero_acc2(acc);
      gemm_w8(spw, Ss, acc, lane, c0w);
      // s = acc + sp_b -> As
      #pragma unroll
      for(int fc = 0; fc < 2; ++fc){
        const int col = c0w + fc*16 + lr;
        const float sb = sb_[col];
        #pragma unroll
        for(int fr = 0; fr < 4; ++fr){
          const int row = fr*16 + rb;
          unsigned p0 = pk_bf16(acc[fr][fc][0] + sb, acc[fr][fc][1] + sb);
          unsigned p1 = pk_bf16(acc[fr][fc][2] + sb, acc[fr][fc][3] + sb);
          *(unsigned short*)(As + swzA(row+0, col*2)) = (unsigned short)p0;
          *(unsigned short*)(As + swzA(row+1, col*2)) = (unsigned short)(p0 >> 16);
          *(unsigned short*)(As + swzA(row+2, col*2)) = (unsigned short)p1;
          *(unsigned short*)(As + swzA(row+3, col*2)) = (unsigned short)(p1 >> 16);
        }
      }
      __syncthreads();                                 // S3
      // ---- scan (thread = channel, tid<256), chunked 16 ----
      if(tid < 256){
        #pragma unroll
        for(int c4 = 0; c4 < 4; ++c4){
          const int base = c4*16;
          float v[16];
          #pragma unroll
          for(int j = 0; j < 16; ++j)
            v[j] = bf2f(*(const unsigned short*)(As + swzA(base+j, tid*2)));
          #pragma unroll
          for(int j = 0; j < 16; ++j){ st = st*dc + v[j]; v[j] = st; }
          #pragma unroll
          for(int j = 0; j < 8; ++j){
            unsigned p = pk_bf16(v[2*j], v[2*j+1]);
            *(unsigned short*)(As + swzA(base+2*j,   tid*2)) = (unsigned short)p;
            *(unsigned short*)(As + swzA(base+2*j+1, tid*2)) = (unsigned short)(p >> 16);
          }
        }
      }
      __syncthreads();                                 // S4
      zero_acc2(acc);
      gemm_w8(spT, As, acc, lane, c0w);                // y1 = states@sp_w
      __syncthreads();                                 // S5
      // y = acc + D*xg (xg from Ss) -> As
      #pragma unroll
      for(int fc = 0; fc < 2; ++fc){
        const int col = c0w + fc*16 + lr;
        const float Dv = Dv_[col];
        #pragma unroll
        for(int fr = 0; fr < 4; ++fr){
          const int row = fr*16 + rb;
          float y0 = acc[fr][fc][0] + Dv*bf2f(*(const unsigned short*)(Ss + swzA(row+0, col*2)));
          float y1 = acc[fr][fc][1] + Dv*bf2f(*(const unsigned short*)(Ss + swzA(row+1, col*2)));
          float y2 = acc[fr][fc][2] + Dv*bf2f(*(const unsigned short*)(Ss + swzA(row+2, col*2)));
          float y3 = acc[fr][fc][3] + Dv*bf2f(*(const unsigned short*)(Ss + swzA(row+3, col*2)));
          unsigned p0 = pk_bf16(y0, y1), p1 = pk_bf16(y2, y3);
          *(unsigned short*)(As + swzA(row+0, col*2)) = (unsigned short)p0;
          *(unsigned short*)(As + swzA(row+1, col*2)) = (unsigned short)(p0 >> 16);
          *(unsigned short*)(As + swzA(row+2, col*2)) = (unsigned short)p1;
          *(unsigned short*)(As + swzA(row+3, col*2)) = (unsigned short)(p1 >> 16);
        }
      }
      __syncthreads();                                 // S6
      zero_acc2(acc);
      gemm_w8(opw, As, acc, lane, c0w);                // @op^T
      // acc + op_b -> Ss
      #pragma unroll
      for(int fc = 0; fc < 2; ++fc){
        const int col = c0w + fc*16 + lr;
        const float ob = ob_[col];
        #pragma unroll
        for(int fr = 0; fr < 4; ++fr){
          const int row = fr*16 + rb;
          unsigned p0 = pk_bf16(acc[fr][fc][0] + ob, acc[fr][fc][1] + ob);
          unsigned p1 = pk_bf16(acc[fr][fc][2] + ob, acc[fr][fc][3] + ob);
          *(unsigned short*)(Ss + swzA(row+0, col*2)) = (unsigned short)p0;
          *(unsigned short*)(Ss + swzA(row+1, col*2)) = (unsigned short)(p0 >> 16);
          *(unsigned short*)(Ss + swzA(row+2, col*2)) = (unsigned short)p1;
          *(unsigned short*)(Ss + swzA(row+3, col*2)) = (unsigned short)(p1 >> 16);
        }
      }
      __syncthreads();                                 // S7
      // h += (y@op^T + op_b), coalesced RMW from Ss (4 x 16B/thread)
      {
        char* dst = (char*)(h_g + (size_t)m0*DMODEL);
        #pragma unroll
        for(int i = 0; i < 4; ++i){
          const unsigned flat = (unsigned)(i*8192 + tid*16);
          const unsigned row = flat >> 9;
          short8 a = *(const short8*)(Ss + (flat ^ ((row & 7u) << 4)));
          short8 hv = *(const short8*)(dst + flat);
          u32x4 o;
          #pragma unroll
          for(int j = 0; j < 4; ++j){
            float s0 = bf2f((unsigned short)a[2*j])   + bf2f((unsigned short)hv[2*j]);
            float s1 = bf2f((unsigned short)a[2*j+1]) + bf2f((unsigned short)hv[2*j+1]);
            o[j] = pk_bf16(s0, s1);
          }
          *(u32x4*)(dst + flat) = o;
        }
      }
      // next Phase A writes As only after S7 (As reads done); Ss fenced by S1
    }
  }
}

// ---------------- out = gelu(LN(h[:,511,:] @ out_w^T + out_b)) (proven) ----------------
__global__ __launch_bounds__(256) void k_out(
    const unsigned short* __restrict__ h_g,
    const unsigned short* __restrict__ out_wb,
    const float* __restrict__ out_bv,
    const float* __restrict__ ln_gv, const float* __restrict__ ln_bv,
    float* __restrict__ out_g)
{
  __shared__ char smem[65536];
  char* As = smem; char* Bs = smem + 32768;
  const int tid = threadIdx.x;
  const int r0 = blockIdx.x * 64;
  const int lane = tid & 63, c0w = (tid>>6)*64, lr = lane & 15, rb = (lane>>4)*4;
  {
    const int r = tid >> 2, c0 = (tid & 3) * 64;
    const unsigned short* src = h_g + ((size_t)(r0 + r)*KSEQ + (KSEQ-1))*DMODEL + c0;
    #pragma unroll
    for(int i = 0; i < 8; ++i){
      short8 v = *(const short8*)(src + i*8);
      *(short8*)(As + swzA(r, c0*2 + i*16)) = v;
    }
  }
  f32x4 acc[4][4]; zero_acc(acc);
  gemm_64x256<4>(out_wb, As, Bs, acc, tid);
  __syncthreads();
  #pragma unroll
  for(int fc = 0; fc < 4; ++fc){
    const int col = c0w + fc*16 + lr;
    const float bb = out_bv[col];
    #pragma unroll
    for(int fr = 0; fr < 4; ++fr)
      #pragma unroll
      for(int rg = 0; rg < 4; ++rg){
        const int row = fr*16 + rb + rg;
        *(float*)(smem + (((unsigned)(row*1024 + col*4)) ^ ((row&7)<<4))) = acc[fr][fc][rg] + bb;
      }
  }
  __syncthreads();
  {
    const int r = tid >> 2, c0 = (tid & 3) * 64;
    float vals[64]; float sm = 0.f, sq = 0.f;
    #pragma unroll
    for(int i = 0; i < 16; ++i){
      float4 v = *(const float4*)(smem + (((unsigned)(r*1024 + (c0 + i*4)*4)) ^ ((r&7)<<4)));
      vals[4*i]=v.x; vals[4*i+1]=v.y; vals[4*i+2]=v.z; vals[4*i+3]=v.w;
    }
    #pragma unroll
    for(int i = 0; i < 64; ++i){ sm += vals[i]; sq += vals[i]*vals[i]; }
    sm += __shfl_xor(sm, 1); sm += __shfl_xor(sm, 2);
    sq += __shfl_xor(sq, 1); sq += __shfl_xor(sq, 2);
    const float mu = sm * (1.f/256.f);
    const float rstd = rsqrtf(sq * (1.f/256.f) - mu*mu + 1e-5f);
    float* dst = out_g + (size_t)(r0 + r)*DMODEL + c0;
    #pragma unroll
    for(int i = 0; i < 16; ++i){
      float4 o;
      o.x = gelu_f((vals[4*i+0]-mu)*rstd*ln_gv[c0+i*4+0] + ln_bv[c0+i*4+0]);
      o.y = gelu_f((vals[4*i+1]-mu)*rstd*ln_gv[c0+i*4+1] + ln_bv[c0+i*4+1]);
      o.z = gelu_f((vals[4*i+2]-mu)*rstd*ln_gv[c0+i*4+2] + ln_bv[c0+i*4+2]);
      o.w = gelu_f((vals[4*i+3]-mu)*rstd*ln_gv[c0+i*4+3] + ln_bv[c0+i*4+3]);
      *(float4*)(dst + i*4) = o;
    }
  }
}

extern "C" void kernel_launch(void* const* d_in, const int* in_sizes, int n_in,
                              void* d_out, int out_size, void* d_ws, size_t ws_size,
                              hipStream_t stream) {
  (void)in_sizes; (void)n_in; (void)out_size; (void)ws_size;
  const float* x        = (const float*)d_in[0];
  const float* in_w     = (const float*)d_in[1];
  const float* in_b     = (const float*)d_in[2];
  const float* in_ln_g  = (const float*)d_in[3];
  const float* in_ln_b  = (const float*)d_in[4];
  const float* ln_g     = (const float*)d_in[5];
  const float* ln_b     = (const float*)d_in[6];
  const float* gate_w   = (const float*)d_in[7];
  const float* gate_b   = (const float*)d_in[8];
  const float* sp_w     = (const float*)d_in[9];
  const float* sp_b     = (const float*)d_in[10];
  const float* op_w     = (const float*)d_in[11];
  const float* op_b     = (const float*)d_in[12];
  const float* A_log    = (const float*)d_in[13];
  const float* Dp       = (const float*)d_in[14];
  const float* out_w    = (const float*)d_in[15];
  const float* out_b    = (const float*)d_in[16];
  const float* out_ln_g = (const float*)d_in[17];
  const float* out_ln_b = (const float*)d_in[18];

  char* ws = (char*)d_ws;
  // ~133.7 MiB workspace (proven budget)
  unsigned short* h_g       = (unsigned short*)(ws + 0);           // 128 MiB
  float*          decay     = (float*)(ws + 134217728);            // 2 KiB
  unsigned short* wbase     = (unsigned short*)(ws + 134219776);   // ~1.2 MiB
  unsigned short* in_wb  = wbase;               // 32768
  unsigned short* gate_wb= in_wb  + 32768;      // 2*65536
  unsigned short* sp_wb  = gate_wb+ 131072;
  unsigned short* sp_wTb = sp_wb  + 131072;
  unsigned short* op_wb  = sp_wTb + 131072;
  unsigned short* out_wb = op_wb  + 131072;     // 65536

  // prep
  k_cvt_inw<<<128, 256, 0, stream>>>(in_w, in_wb);
  k_cvt<<<512, 256, 0, stream>>>(gate_w, gate_wb, 131072);
  k_cvt<<<512, 256, 0, stream>>>(sp_w,   sp_wb,   131072);
  k_cvt<<<512, 256, 0, stream>>>(op_w,   op_wb,   131072);
  k_cvt<<<256, 256, 0, stream>>>(out_w,  out_wb,  65536);
  k_spT<<<dim3(256,2), 256, 0, stream>>>(sp_w, sp_wTb);
  k_decay<<<512, 256, 0, stream>>>(A_log, decay);

  // pipeline
  k_in_proj<<<MTOT/64, 256, 0, stream>>>(x, in_wb, in_b, in_ln_g, in_ln_b, h_g);
  k_layers<<<NSEQ, 512, 0, stream>>>(h_g, gate_wb, sp_wb, sp_wTb, op_wb,
      ln_g, ln_b, gate_b, sp_b, decay, Dp, op_b);
  k_out<<<NSEQ/64, 256, 0, stream>>>(h_g, out_wb, out_b, out_ln_g, out_ln_b, (float*)d_out);
}

// Round 15
// 1032.126 us; speedup vs baseline: 1.3307x; 1.3043x over previous
//
#include <hip/hip_runtime.h>
#include <hip/hip_bf16.h>

// MambaEncoder on MI355X — v15: v10 base + TWO-TILE SOFTWARE PIPELINE.
// v13/v14 lesson: 2 blocks/CU unreachable without spill -> occupancy closed.
// Instead: tile k+1's front phases (LN,gate,sp) are independent of tile k's
// back phases (scan,spT/y,op/RMW) -> run concurrently in 3 superphases/tile
// (was 7 barriers): SP1 LN(k+1)||scan(k); SP2 spT+y(k)||gate+xg(k+1);
// SP3 op+RMW(k)||sp+s(k+1). Ping-pong As/Ss pairs (128KB LDS, 1 blk/CU),
// (512,2) keeps 256-reg budget (dual accs, no spill). y-epi in-place in Ss
// and wave-local h-RMW are v12-proven. ws ~133.7MiB.

typedef __attribute__((ext_vector_type(8))) __bf16 bf16x8;
typedef __attribute__((ext_vector_type(8))) short short8;
typedef __attribute__((ext_vector_type(4))) float f32x4;
typedef __attribute__((ext_vector_type(4))) unsigned u32x4;

#define NSEQ 512
#define KSEQ 512
#define FIN 96
#define DMODEL 256
#define MTOT (NSEQ*KSEQ)

__device__ __forceinline__ unsigned short f2bf(float f){
  union { float f; unsigned u; } v; v.f = f;
  unsigned r = (v.u + 0x7FFFu + ((v.u >> 16) & 1u)) >> 16;
  return (unsigned short)r;
}
__device__ __forceinline__ float bf2f(unsigned short b){
  union { unsigned u; float f; } v; v.u = ((unsigned)b) << 16; return v.f;
}
__device__ __forceinline__ unsigned pk_bf16(float lo, float hi){
  unsigned r;
  asm("v_cvt_pk_bf16_f32 %0, %1, %2" : "=v"(r) : "v"(lo), "v"(hi));
  return r;
}
__device__ __forceinline__ float gelu_f(float x){
  return 0.5f * x * (1.0f + erff(x * 0.70710678118654752440f));
}
__device__ __forceinline__ float silu_f(float x){
  return x / (1.0f + __expf(-x));
}
__device__ __forceinline__ unsigned swzA(int row, int kbyte){   // [64][256] bf16, 512B stride
  return ((unsigned)(row*512 + kbyte)) ^ (unsigned)((row & 7) << 4);
}
__device__ __forceinline__ unsigned swzB(int n, int kbyte){     // [256][64] bf16
  return ((unsigned)(n*128 + kbyte)) ^ (unsigned)((n & 7) << 4);
}

// 8-wave col-split GEMM: acc[4][2] += A(64x256 LDS, swzA) @ W[cols c0..c0+32]^T
// B direct from global (cache-resident), 4-deep chunk prefetch ring. (v10-proven)
__device__ __forceinline__ void gemm_w8(const unsigned short* __restrict__ wb,
                                        const char* As, f32x4 (&acc)[4][2],
                                        int lane, int c0)
{
  const int lr  = lane & 15;
  const int lk8 = (lane >> 4) * 8;
  const unsigned short* bp = wb + (size_t)(c0 + lr)*256 + lk8;   // +fc*4096 +kc*32
  bf16x8 bb[4][2];
  #pragma unroll
  for(int p = 0; p < 4; ++p)
    #pragma unroll
    for(int fc = 0; fc < 2; ++fc)
      bb[p][fc] = *(const bf16x8*)(bp + fc*4096 + p*32);
  #pragma unroll
  for(int kc = 0; kc < 8; ++kc){
    bf16x8 af[4];
    #pragma unroll
    for(int fr = 0; fr < 4; ++fr)
      af[fr] = *(const bf16x8*)(As + swzA(fr*16 + lr, kc*64 + lk8*2));
    #pragma unroll
    for(int fr = 0; fr < 4; ++fr)
      #pragma unroll
      for(int fc = 0; fc < 2; ++fc)
        acc[fr][fc] = __builtin_amdgcn_mfma_f32_16x16x32_bf16(af[fr], bb[kc&3][fc], acc[fr][fc], 0, 0, 0);
    if(kc < 4){
      #pragma unroll
      for(int fc = 0; fc < 2; ++fc)
        bb[kc&3][fc] = *(const bf16x8*)(bp + fc*4096 + (kc+4)*32);
    }
  }
}

__device__ __forceinline__ void zero_acc2(f32x4 (&acc)[4][2]){
  #pragma unroll
  for(int a=0;a<4;++a)
    #pragma unroll
    for(int b=0;b<2;++b)
      acc[a][b] = (f32x4){0.f,0.f,0.f,0.f};
}
__device__ __forceinline__ void zero_acc(f32x4 (&acc)[4][4]){
  #pragma unroll
  for(int a=0;a<4;++a)
    #pragma unroll
    for(int b=0;b<4;++b)
      acc[a][b] = (f32x4){0.f,0.f,0.f,0.f};
}

// ---------------- k_layers phase helpers (bodies v10/v12-proven) ----------------
// LN(h tile m0) -> z bf16 into A (8 thr/row)
__device__ __forceinline__ void ph_ln(const unsigned short* __restrict__ h_g, int m0,
    char* A, const float* __restrict__ lg, const float* __restrict__ lb,
    int rA, int cAh)
{
  const unsigned short* src = h_g + (size_t)(m0 + rA)*DMODEL + cAh;
  short8 hv[4];
  #pragma unroll
  for(int i = 0; i < 4; ++i) hv[i] = *(const short8*)(src + i*8);
  float sm = 0.f, sq = 0.f;
  #pragma unroll
  for(int i = 0; i < 4; ++i)
    #pragma unroll
    for(int j = 0; j < 8; ++j){
      float v = bf2f((unsigned short)hv[i][j]); sm += v; sq += v*v;
    }
  sm += __shfl_xor(sm, 1); sm += __shfl_xor(sm, 2); sm += __shfl_xor(sm, 4);
  sq += __shfl_xor(sq, 1); sq += __shfl_xor(sq, 2); sq += __shfl_xor(sq, 4);
  const float mu = sm * (1.f/256.f);
  const float rstd = rsqrtf(sq * (1.f/256.f) - mu*mu + 1e-5f);
  #pragma unroll
  for(int i = 0; i < 4; ++i){
    float z[8];
    #pragma unroll
    for(int j = 0; j < 8; ++j){
      const int c = cAh + i*8 + j;
      z[j] = (bf2f((unsigned short)hv[i][j])-mu)*rstd*lg[c] + lb[c];
    }
    u32x4 zz;
    zz[0] = pk_bf16(z[0],z[1]); zz[1] = pk_bf16(z[2],z[3]);
    zz[2] = pk_bf16(z[4],z[5]); zz[3] = pk_bf16(z[6],z[7]);
    *(u32x4*)(A + swzA(rA, cAh*2 + i*16)) = zz;
  }
}

// gate GEMM(A) -> xg=silu -> S (own cols)
__device__ __forceinline__ void ph_gate(const unsigned short* __restrict__ gw,
    const char* A, char* S, const float* __restrict__ gb_,
    int lane, int c0w, int lr, int rb)
{
  f32x4 acc[4][2]; zero_acc2(acc);
  gemm_w8(gw, A, acc, lane, c0w);
  #pragma unroll
  for(int fc = 0; fc < 2; ++fc){
    const int col = c0w + fc*16 + lr;
    const float gb = gb_[col];
    #pragma unroll
    for(int fr = 0; fr < 4; ++fr){
      const int row = fr*16 + rb;
      float v0 = silu_f(acc[fr][fc][0] + gb), v1 = silu_f(acc[fr][fc][1] + gb);
      float v2 = silu_f(acc[fr][fc][2] + gb), v3 = silu_f(acc[fr][fc][3] + gb);
      unsigned p0 = pk_bf16(v0, v1), p1 = pk_bf16(v2, v3);
      *(unsigned short*)(S + swzA(row+0, col*2)) = (unsigned short)p0;
      *(unsigned short*)(S + swzA(row+1, col*2)) = (unsigned short)(p0 >> 16);
      *(unsigned short*)(S + swzA(row+2, col*2)) = (unsigned short)p1;
      *(unsigned short*)(S + swzA(row+3, col*2)) = (unsigned short)(p1 >> 16);
    }
  }
}

// sp GEMM(S=xg) -> s=+sp_b -> A (own cols)
__device__ __forceinline__ void ph_sp(const unsigned short* __restrict__ spw,
    const char* S, char* A, const float* __restrict__ sb_,
    int lane, int c0w, int lr, int rb)
{
  f32x4 acc[4][2]; zero_acc2(acc);
  gemm_w8(spw, S, acc, lane, c0w);
  #pragma unroll
  for(int fc = 0; fc < 2; ++fc){
    const int col = c0w + fc*16 + lr;
    const float sb = sb_[col];
    #pragma unroll
    for(int fr = 0; fr < 4; ++fr){
      const int row = fr*16 + rb;
      unsigned p0 = pk_bf16(acc[fr][fc][0] + sb, acc[fr][fc][1] + sb);
      unsigned p1 = pk_bf16(acc[fr][fc][2] + sb, acc[fr][fc][3] + sb);
      *(unsigned short*)(A + swzA(row+0, col*2)) = (unsigned short)p0;
      *(unsigned short*)(A + swzA(row+1, col*2)) = (unsigned short)(p0 >> 16);
      *(unsigned short*)(A + swzA(row+2, col*2)) = (unsigned short)p1;
      *(unsigned short*)(A + swzA(row+3, col*2)) = (unsigned short)(p1 >> 16);
    }
  }
}

// scan in A (thread=channel, tid<256), chunked 16
__device__ __forceinline__ void ph_scan(char* A, float& st, float dc, int tid)
{
  if(tid < 256){
    #pragma unroll
    for(int c4 = 0; c4 < 4; ++c4){
      const int base = c4*16;
      float v[16];
      #pragma unroll
      for(int j = 0; j < 16; ++j)
        v[j] = bf2f(*(const unsigned short*)(A + swzA(base+j, tid*2)));
      #pragma unroll
      for(int j = 0; j < 16; ++j){ st = st*dc + v[j]; v[j] = st; }
      #pragma unroll
      for(int j = 0; j < 8; ++j){
        unsigned p = pk_bf16(v[2*j], v[2*j+1]);
        *(unsigned short*)(A + swzA(base+2*j,   tid*2)) = (unsigned short)p;
        *(unsigned short*)(A + swzA(base+2*j+1, tid*2)) = (unsigned short)(p >> 16);
      }
    }
  }
}

// spT GEMM(A=states) -> y = acc + D*xg, IN-PLACE in S (read+write own cols)
__device__ __forceinline__ void ph_spt_y(const unsigned short* __restrict__ spT,
    const char* A, char* S, const float* __restrict__ Dv_,
    int lane, int c0w, int lr, int rb)
{
  f32x4 acc[4][2]; zero_acc2(acc);
  gemm_w8(spT, A, acc, lane, c0w);
  #pragma unroll
  for(int fc = 0; fc < 2; ++fc){
    const int col = c0w + fc*16 + lr;
    const float Dv = Dv_[col];
    #pragma unroll
    for(int fr = 0; fr < 4; ++fr){
      const int row = fr*16 + rb;
      float y0 = acc[fr][fc][0] + Dv*bf2f(*(const unsigned short*)(S + swzA(row+0, col*2)));
      float y1 = acc[fr][fc][1] + Dv*bf2f(*(const unsigned short*)(S + swzA(row+1, col*2)));
      float y2 = acc[fr][fc][2] + Dv*bf2f(*(const unsigned short*)(S + swzA(row+2, col*2)));
      float y3 = acc[fr][fc][3] + Dv*bf2f(*(const unsigned short*)(S + swzA(row+3, col*2)));
      unsigned p0 = pk_bf16(y0, y1), p1 = pk_bf16(y2, y3);
      *(unsigned short*)(S + swzA(row+0, col*2)) = (unsigned short)p0;
      *(unsigned short*)(S + swzA(row+1, col*2)) = (unsigned short)(p0 >> 16);
      *(unsigned short*)(S + swzA(row+2, col*2)) = (unsigned short)p1;
      *(unsigned short*)(S + swzA(row+3, col*2)) = (unsigned short)(p1 >> 16);
    }
  }
}

// op GEMM(S=y) -> +op_b -> A own cols -> wave-local h-RMW (own 32 cols)
__device__ __forceinline__ void ph_op_rmw(const unsigned short* __restrict__ opw,
    const char* S, char* A, const float* __restrict__ ob_,
    unsigned short* __restrict__ h_g, int m0,
    int lane, int c0w, int lr, int rb)
{
  f32x4 acc[4][2]; zero_acc2(acc);
  gemm_w8(opw, S, acc, lane, c0w);
  #pragma unroll
  for(int fc = 0; fc < 2; ++fc){
    const int col = c0w + fc*16 + lr;
    const float ob = ob_[col];
    #pragma unroll
    for(int fr = 0; fr < 4; ++fr){
      const int row = fr*16 + rb;
      unsigned p0 = pk_bf16(acc[fr][fc][0] + ob, acc[fr][fc][1] + ob);
      unsigned p1 = pk_bf16(acc[fr][fc][2] + ob, acc[fr][fc][3] + ob);
      *(unsigned short*)(A + swzA(row+0, col*2)) = (unsigned short)p0;
      *(unsigned short*)(A + swzA(row+1, col*2)) = (unsigned short)(p0 >> 16);
      *(unsigned short*)(A + swzA(row+2, col*2)) = (unsigned short)p1;
      *(unsigned short*)(A + swzA(row+3, col*2)) = (unsigned short)(p1 >> 16);
    }
  }
  // wave-local RMW (v12-proven): own 32 cols, 64B sector chunks per row
  {
    char* hb = (char*)(h_g + (size_t)m0*DMODEL);
    const int cl = lane & 3;
    const int rbase = lane >> 2;
    #pragma unroll
    for(int p = 0; p < 4; ++p){
      const int row = p*16 + rbase;
      const unsigned gof = (unsigned)(row*512 + c0w*2 + cl*16);
      short8 a = *(const short8*)(A + swzA(row, c0w*2 + cl*16));
      short8 hv = *(const short8*)(hb + gof);
      u32x4 o;
      #pragma unroll
      for(int j = 0; j < 4; ++j){
        float s0 = bf2f((unsigned short)a[2*j])   + bf2f((unsigned short)hv[2*j]);
        float s1 = bf2f((unsigned short)a[2*j+1]) + bf2f((unsigned short)hv[2*j+1]);
        o[j] = pk_bf16(s0, s1);
      }
      *(u32x4*)(hb + gof) = o;
    }
  }
}

// LDS-staged GEMM (k_in_proj / k_out only, proven, 256 thr)
template<int KCH>
__device__ __forceinline__ void gemm_64x256(const unsigned short* __restrict__ wb,
                                            char* As, char* Bs,
                                            f32x4 (&acc)[4][4], int tid)
{
  const int lane = tid & 63;
  const int c0   = (tid >> 6) * 64;
  const int lr   = lane & 15;
  const int lk16 = (lane >> 4) * 16;
  #pragma unroll
  for(int kc = 0; kc < KCH; ++kc){
    __syncthreads();
    {
      const unsigned short* src = wb + (size_t)tid * (KCH*64) + kc*64;
      #pragma unroll
      for(int i = 0; i < 8; ++i){
        short8 v = *(const short8*)(src + i*8);
        *(short8*)(Bs + swzB(tid, i*16)) = v;
      }
    }
    __syncthreads();
    #pragma unroll
    for(int t2 = 0; t2 < 2; ++t2){
      bf16x8 af[4], bfr[4];
      #pragma unroll
      for(int fr = 0; fr < 4; ++fr)
        af[fr] = *(const bf16x8*)(As + swzA(fr*16 + lr, kc*128 + t2*64 + lk16));
      #pragma unroll
      for(int fc = 0; fc < 4; ++fc)
        bfr[fc] = *(const bf16x8*)(Bs + swzB(c0 + fc*16 + lr, t2*64 + lk16));
      #pragma unroll
      for(int fr = 0; fr < 4; ++fr)
        #pragma unroll
        for(int fc = 0; fc < 4; ++fc)
          acc[fr][fc] = __builtin_amdgcn_mfma_f32_16x16x32_bf16(af[fr], bfr[fc], acc[fr][fc], 0, 0, 0);
    }
  }
}

// ---------------- prep kernels ----------------
__global__ void k_cvt(const float* __restrict__ s, unsigned short* __restrict__ d, int n){
  int i = blockIdx.x*256 + threadIdx.x;
  if(i < n) d[i] = f2bf(s[i]);
}
__global__ void k_cvt_inw(const float* __restrict__ w, unsigned short* __restrict__ d){
  int i = blockIdx.x*256 + threadIdx.x;
  int n = i >> 7, f = i & 127;
  d[i] = (f < 96) ? f2bf(w[n*96 + f]) : (unsigned short)0;
}
__global__ void k_spT(const float* __restrict__ spw, unsigned short* __restrict__ d){
  int l = blockIdx.y;
  int i = blockIdx.x*256 + threadIdx.x;
  int dd = i >> 8, ss = i & 255;
  d[l*65536 + i] = f2bf(spw[l*65536 + ss*256 + dd]);
}
__global__ void k_decay(const float* __restrict__ A_log, float* __restrict__ decay){
  __shared__ float red[4];
  const int b = blockIdx.x;
  const int tid = threadIdx.x;
  float v = expf(A_log[(size_t)b*256 + tid]);
  #pragma unroll
  for(int o = 32; o >= 1; o >>= 1) v += __shfl_xor(v, o);
  if((tid & 63) == 0) red[tid >> 6] = v;
  __syncthreads();
  if(tid == 0){
    float s = red[0] + red[1] + red[2] + red[3];
    decay[b] = expf(-s * (1.f/256.f));
  }
}

// ---------------- h = gelu(LN(x @ in_w^T + in_b)) -> bf16 (proven) ----------------
__global__ __launch_bounds__(256) void k_in_proj(
    const float* __restrict__ x_g,
    const unsigned short* __restrict__ in_wb,
    const float* __restrict__ in_b,
    const float* __restrict__ ln_gv, const float* __restrict__ ln_bv,
    unsigned short* __restrict__ h_g)
{
  __shared__ char smem[65536];
  char* As = smem; char* Bs = smem + 32768;
  const int tid = threadIdx.x;
  const int m0 = blockIdx.x * 64;
  const int lane = tid & 63, c0w = (tid>>6)*64, lr = lane & 15, rb = (lane>>4)*4;
  {
    const int r = tid >> 2, cq = tid & 3;
    const float* src = x_g + (size_t)(m0 + r)*FIN + cq*24;
    unsigned short tmp[24] __attribute__((aligned(16)));
    #pragma unroll
    for(int i = 0; i < 6; ++i){
      float4 v = *(const float4*)(src + i*4);
      tmp[4*i]=f2bf(v.x); tmp[4*i+1]=f2bf(v.y); tmp[4*i+2]=f2bf(v.z); tmp[4*i+3]=f2bf(v.w);
    }
    #pragma unroll
    for(int i = 0; i < 3; ++i)
      *(short8*)(As + swzA(r, cq*48 + i*16)) = *(const short8*)(tmp + i*8);
    if(cq == 3){
      short8 z8 = {0,0,0,0,0,0,0,0};
      #pragma unroll
      for(int i = 0; i < 4; ++i)
        *(short8*)(As + swzA(r, 192 + i*16)) = z8;
    }
  }
  f32x4 acc[4][4]; zero_acc(acc);
  gemm_64x256<2>(in_wb, As, Bs, acc, tid);
  __syncthreads();
  #pragma unroll
  for(int fc = 0; fc < 4; ++fc){
    const int col = c0w + fc*16 + lr;
    const float bb = in_b[col];
    #pragma unroll
    for(int fr = 0; fr < 4; ++fr)
      #pragma unroll
      for(int rg = 0; rg < 4; ++rg){
        const int row = fr*16 + rb + rg;
        *(float*)(smem + (((unsigned)(row*1024 + col*4)) ^ ((row&7)<<4))) = acc[fr][fc][rg] + bb;
      }
  }
  __syncthreads();
  {
    const int r = tid >> 2, c0 = (tid & 3) * 64;
    float vals[64]; float sm = 0.f, sq = 0.f;
    #pragma unroll
    for(int i = 0; i < 16; ++i){
      float4 v = *(const float4*)(smem + (((unsigned)(r*1024 + (c0 + i*4)*4)) ^ ((r&7)<<4)));
      vals[4*i]=v.x; vals[4*i+1]=v.y; vals[4*i+2]=v.z; vals[4*i+3]=v.w;
    }
    #pragma unroll
    for(int i = 0; i < 64; ++i){ sm += vals[i]; sq += vals[i]*vals[i]; }
    sm += __shfl_xor(sm, 1); sm += __shfl_xor(sm, 2);
    sq += __shfl_xor(sq, 1); sq += __shfl_xor(sq, 2);
    const float mu = sm * (1.f/256.f);
    const float rstd = rsqrtf(sq * (1.f/256.f) - mu*mu + 1e-5f);
    unsigned short* dst = h_g + (size_t)(m0 + r)*DMODEL + c0;
    #pragma unroll
    for(int i = 0; i < 8; ++i){
      float g[8];
      #pragma unroll
      for(int j = 0; j < 8; ++j){
        const int c = c0 + i*8 + j;
        g[j] = gelu_f((vals[i*8+j]-mu)*rstd*ln_gv[c] + ln_bv[c]);
      }
      u32x4 o;
      o[0] = pk_bf16(g[0],g[1]); o[1] = pk_bf16(g[2],g[3]);
      o[2] = pk_bf16(g[4],g[5]); o[3] = pk_bf16(g[6],g[7]);
      *(u32x4*)(dst + i*8) = o;
    }
  }
}

// ---------------- BOTH layers, two-tile pipelined: block = sequence, 512 thr ----------------
__global__ __launch_bounds__(512,2) void k_layers(
    unsigned short* __restrict__ h_g,
    const unsigned short* __restrict__ gate_w0,
    const unsigned short* __restrict__ sp_w0,
    const unsigned short* __restrict__ spT_w0,
    const unsigned short* __restrict__ op_w0,
    const float* __restrict__ ln_g0, const float* __restrict__ ln_b0,
    const float* __restrict__ gate_b0, const float* __restrict__ sp_b0,
    const float* __restrict__ decay0, const float* __restrict__ D0,
    const float* __restrict__ op_b0)
{
  __shared__ char As0[32768];
  __shared__ char Ss0[32768];
  __shared__ char As1[32768];
  __shared__ char Ss1[32768];
  const int tid = threadIdx.x;
  const int n = blockIdx.x;
  const int lane = tid & 63;
  const int c0w = (tid >> 6) * 32;            // wave -> 32 output cols
  const int lr = lane & 15, rb = (lane>>4)*4;
  const int rA = tid >> 3, cAh = (tid & 7) * 32;   // LN: 8 thr/row
  float st = 0.f;                              // scan state across layers

  #pragma unroll 1
  for(int l = 0; l < 2; ++l){
    const unsigned short* gw  = gate_w0 + l*65536;
    const unsigned short* spw = sp_w0   + l*65536;
    const unsigned short* spT = spT_w0  + l*65536;
    const unsigned short* opw = op_w0   + l*65536;
    const float* lg  = ln_g0   + l*256;
    const float* lb  = ln_b0   + l*256;
    const float* gb_ = gate_b0 + l*256;
    const float* sb_ = sp_b0   + l*256;
    const float* Dv_ = D0      + l*256;
    const float* ob_ = op_b0   + l*256;
    const float dc = decay0[l*256 + (tid & 255)];
    const int mL = n*KSEQ;

    // prologue: tile 0 front phases on buffer pair 0
    ph_ln(h_g, mL, As0, lg, lb, rA, cAh);
    __syncthreads();
    ph_gate(gw, As0, Ss0, gb_, lane, c0w, lr, rb);
    __syncthreads();
    ph_sp(spw, Ss0, As0, sb_, lane, c0w, lr, rb);
    __syncthreads();

    #pragma unroll 1
    for(int kb = 0; kb < 8; ++kb){
      char* Ab = (kb & 1) ? As1 : As0;
      char* Sb = (kb & 1) ? Ss1 : Ss0;
      char* Af = (kb & 1) ? As0 : As1;
      char* Sf = (kb & 1) ? Ss0 : Ss1;
      const int m0 = mL + kb*64;
      // SP1: front LN (global loads early) || back scan (serial LDS chain)
      if(kb < 7) ph_ln(h_g, m0 + 64, Af, lg, lb, rA, cAh);
      ph_scan(Ab, st, dc, tid);
      __syncthreads();
      // SP2: back spT + y-epi (Ss in place) || front gate + xg-epi
      ph_spt_y(spT, Ab, Sb, Dv_, lane, c0w, lr, rb);
      if(kb < 7) ph_gate(gw, Af, Sf, gb_, lane, c0w, lr, rb);
      __syncthreads();
      // SP3: back op + op-epi + h-RMW || front sp + s-epi
      ph_op_rmw(opw, Sb, Ab, ob_, h_g, m0, lane, c0w, lr, rb);
      if(kb < 7) ph_sp(spw, Sf, Af, sb_, lane, c0w, lr, rb);
      __syncthreads();
    }
  }
}

// ---------------- out = gelu(LN(h[:,511,:] @ out_w^T + out_b)) (proven) ----------------
__global__ __launch_bounds__(256) void k_out(
    const unsigned short* __restrict__ h_g,
    const unsigned short* __restrict__ out_wb,
    const float* __restrict__ out_bv,
    const float* __restrict__ ln_gv, const float* __restrict__ ln_bv,
    float* __restrict__ out_g)
{
  __shared__ char smem[65536];
  char* As = smem; char* Bs = smem + 32768;
  const int tid = threadIdx.x;
  const int r0 = blockIdx.x * 64;
  const int lane = tid & 63, c0w = (tid>>6)*64, lr = lane & 15, rb = (lane>>4)*4;
  {
    const int r = tid >> 2, c0 = (tid & 3) * 64;
    const unsigned short* src = h_g + ((size_t)(r0 + r)*KSEQ + (KSEQ-1))*DMODEL + c0;
    #pragma unroll
    for(int i = 0; i < 8; ++i){
      short8 v = *(const short8*)(src + i*8);
      *(short8*)(As + swzA(r, c0*2 + i*16)) = v;
    }
  }
  f32x4 acc[4][4]; zero_acc(acc);
  gemm_64x256<4>(out_wb, As, Bs, acc, tid);
  __syncthreads();
  #pragma unroll
  for(int fc = 0; fc < 4; ++fc){
    const int col = c0w + fc*16 + lr;
    const float bb = out_bv[col];
    #pragma unroll
    for(int fr = 0; fr < 4; ++fr)
      #pragma unroll
      for(int rg = 0; rg < 4; ++rg){
        const int row = fr*16 + rb + rg;
        *(float*)(smem + (((unsigned)(row*1024 + col*4)) ^ ((row&7)<<4))) = acc[fr][fc][rg] + bb;
      }
  }
  __syncthreads();
  {
    const int r = tid >> 2, c0 = (tid & 3) * 64;
    float vals[64]; float sm = 0.f, sq = 0.f;
    #pragma unroll
    for(int i = 0; i < 16; ++i){
      float4 v = *(const float4*)(smem + (((unsigned)(r*1024 + (c0 + i*4)*4)) ^ ((r&7)<<4)));
      vals[4*i]=v.x; vals[4*i+1]=v.y; vals[4*i+2]=v.z; vals[4*i+3]=v.w;
    }
    #pragma unroll
    for(int i = 0; i < 64; ++i){ sm += vals[i]; sq += vals[i]*vals[i]; }
    sm += __shfl_xor(sm, 1); sm += __shfl_xor(sm, 2);
    sq += __shfl_xor(sq, 1); sq += __shfl_xor(sq, 2);
    const float mu = sm * (1.f/256.f);
    const float rstd = rsqrtf(sq * (1.f/256.f) - mu*mu + 1e-5f);
    float* dst = out_g + (size_t)(r0 + r)*DMODEL + c0;
    #pragma unroll
    for(int i = 0; i < 16; ++i){
      float4 o;
      o.x = gelu_f((vals[4*i+0]-mu)*rstd*ln_gv[c0+i*4+0] + ln_bv[c0+i*4+0]);
      o.y = gelu_f((vals[4*i+1]-mu)*rstd*ln_gv[c0+i*4+1] + ln_bv[c0+i*4+1]);
      o.z = gelu_f((vals[4*i+2]-mu)*rstd*ln_gv[c0+i*4+2] + ln_bv[c0+i*4+2]);
      o.w = gelu_f((vals[4*i+3]-mu)*rstd*ln_gv[c0+i*4+3] + ln_bv[c0+i*4+3]);
      *(float4*)(dst + i*4) = o;
    }
  }
}

extern "C" void kernel_launch(void* const* d_in, const int* in_sizes, int n_in,
                              void* d_out, int out_size, void* d_ws, size_t ws_size,
                              hipStream_t stream) {
  (void)in_sizes; (void)n_in; (void)out_size; (void)ws_size;
  const float* x        = (const float*)d_in[0];
  const float* in_w     = (const float*)d_in[1];
  const float* in_b     = (const float*)d_in[2];
  const float* in_ln_g  = (const float*)d_in[3];
  const float* in_ln_b  = (const float*)d_in[4];
  const float* ln_g     = (const float*)d_in[5];
  const float* ln_b     = (const float*)d_in[6];
  const float* gate_w   = (const float*)d_in[7];
  const float* gate_b   = (const float*)d_in[8];
  const float* sp_w     = (const float*)d_in[9];
  const float* sp_b     = (const float*)d_in[10];
  const float* op_w     = (const float*)d_in[11];
  const float* op_b     = (const float*)d_in[12];
  const float* A_log    = (const float*)d_in[13];
  const float* Dp       = (const float*)d_in[14];
  const float* out_w    = (const float*)d_in[15];
  const float* out_b    = (const float*)d_in[16];
  const float* out_ln_g = (const float*)d_in[17];
  const float* out_ln_b = (const float*)d_in[18];

  char* ws = (char*)d_ws;
  // ~133.7 MiB workspace (proven budget)
  unsigned short* h_g       = (unsigned short*)(ws + 0);           // 128 MiB
  float*          decay     = (float*)(ws + 134217728);            // 2 KiB
  unsigned short* wbase     = (unsigned short*)(ws + 134219776);   // ~1.2 MiB
  unsigned short* in_wb  = wbase;               // 32768
  unsigned short* gate_wb= in_wb  + 32768;      // 2*65536
  unsigned short* sp_wb  = gate_wb+ 131072;
  unsigned short* sp_wTb = sp_wb  + 131072;
  unsigned short* op_wb  = sp_wTb + 131072;
  unsigned short* out_wb = op_wb  + 131072;     // 65536

  // prep
  k_cvt_inw<<<128, 256, 0, stream>>>(in_w, in_wb);
  k_cvt<<<512, 256, 0, stream>>>(gate_w, gate_wb, 131072);
  k_cvt<<<512, 256, 0, stream>>>(sp_w,   sp_wb,   131072);
  k_cvt<<<512, 256, 0, stream>>>(op_w,   op_wb,   131072);
  k_cvt<<<256, 256, 0, stream>>>(out_w,  out_wb,  65536);
  k_spT<<<dim3(256,2), 256, 0, stream>>>(sp_w, sp_wTb);
  k_decay<<<512, 256, 0, stream>>>(A_log, decay);

  // pipeline
  k_in_proj<<<MTOT/64, 256, 0, stream>>>(x, in_wb, in_b, in_ln_g, in_ln_b, h_g);
  k_layers<<<NSEQ, 512, 0, stream>>>(h_g, gate_wb, sp_wb, sp_wTb, op_wb,
      ln_g, ln_b, gate_b, sp_b, decay, Dp, op_b);
  k_out<<<NSEQ/64, 256, 0, stream>>>(h_g, out_wb, out_b, out_ln_g, out_ln_b, (float*)d_out);
}

// Round 16
// 968.481 us; speedup vs baseline: 1.4181x; 1.0657x over previous
//
#include <hip/hip_runtime.h>
#include <hip/hip_bf16.h>

// MambaEncoder on MI355X — v16: v15 (two-tile pipeline, 1032us) + MFMA OPERAND
// SWAP: compute mfma(W_frag, act_frag) so D[m=wcol][n=actrow] -> each lane's 4
// acc values = 4 consecutive cols of one row -> epilogues write ONE b64 per
// (fr,fc) instead of 32 scattered b16 (which were 4-way bank-conflicted:
// rows r and r+8 share banks under the (row&7)<<4 swizzle). y-epi xg read
// likewise becomes one b64. Bit-identical numerics. ws ~133.7MiB.

typedef __attribute__((ext_vector_type(8))) __bf16 bf16x8;
typedef __attribute__((ext_vector_type(8))) short short8;
typedef __attribute__((ext_vector_type(4))) float f32x4;
typedef __attribute__((ext_vector_type(4))) unsigned u32x4;
typedef __attribute__((ext_vector_type(2))) unsigned u32x2;

#define NSEQ 512
#define KSEQ 512
#define FIN 96
#define DMODEL 256
#define MTOT (NSEQ*KSEQ)

__device__ __forceinline__ unsigned short f2bf(float f){
  union { float f; unsigned u; } v; v.f = f;
  unsigned r = (v.u + 0x7FFFu + ((v.u >> 16) & 1u)) >> 16;
  return (unsigned short)r;
}
__device__ __forceinline__ float bf2f(unsigned short b){
  union { unsigned u; float f; } v; v.u = ((unsigned)b) << 16; return v.f;
}
__device__ __forceinline__ unsigned pk_bf16(float lo, float hi){
  unsigned r;
  asm("v_cvt_pk_bf16_f32 %0, %1, %2" : "=v"(r) : "v"(lo), "v"(hi));
  return r;
}
__device__ __forceinline__ float gelu_f(float x){
  return 0.5f * x * (1.0f + erff(x * 0.70710678118654752440f));
}
__device__ __forceinline__ float silu_f(float x){
  return x / (1.0f + __expf(-x));
}
__device__ __forceinline__ unsigned swzA(int row, int kbyte){   // [64][256] bf16, 512B stride
  return ((unsigned)(row*512 + kbyte)) ^ (unsigned)((row & 7) << 4);
}
__device__ __forceinline__ unsigned swzB(int n, int kbyte){     // [256][64] bf16
  return ((unsigned)(n*128 + kbyte)) ^ (unsigned)((n & 7) << 4);
}

// 8-wave col-split GEMM, OPERAND-SWAPPED: acc[fr][fc] = D[wcol-block][actrow-block]
// via mfma(A=weight frag, B=activation frag). acc[fr][fc][reg]:
//   actrow = fr*16 + (lane&15), wcol = c0 + fc*16 + (lane>>4)*4 + reg.
// B direct from global (cache-resident), 4-deep chunk prefetch ring.
__device__ __forceinline__ void gemm_w8(const unsigned short* __restrict__ wb,
                                        const char* As, f32x4 (&acc)[4][2],
                                        int lane, int c0)
{
  const int lr  = lane & 15;
  const int lk8 = (lane >> 4) * 8;
  const unsigned short* bp = wb + (size_t)(c0 + lr)*256 + lk8;   // +fc*4096 +kc*32
  bf16x8 bb[4][2];
  #pragma unroll
  for(int p = 0; p < 4; ++p)
    #pragma unroll
    for(int fc = 0; fc < 2; ++fc)
      bb[p][fc] = *(const bf16x8*)(bp + fc*4096 + p*32);
  #pragma unroll
  for(int kc = 0; kc < 8; ++kc){
    bf16x8 af[4];
    #pragma unroll
    for(int fr = 0; fr < 4; ++fr)
      af[fr] = *(const bf16x8*)(As + swzA(fr*16 + lr, kc*64 + lk8*2));
    #pragma unroll
    for(int fr = 0; fr < 4; ++fr)
      #pragma unroll
      for(int fc = 0; fc < 2; ++fc)
        acc[fr][fc] = __builtin_amdgcn_mfma_f32_16x16x32_bf16(bb[kc&3][fc], af[fr], acc[fr][fc], 0, 0, 0);
    if(kc < 4){
      #pragma unroll
      for(int fc = 0; fc < 2; ++fc)
        bb[kc&3][fc] = *(const bf16x8*)(bp + fc*4096 + (kc+4)*32);
    }
  }
}

__device__ __forceinline__ void zero_acc2(f32x4 (&acc)[4][2]){
  #pragma unroll
  for(int a=0;a<4;++a)
    #pragma unroll
    for(int b=0;b<2;++b)
      acc[a][b] = (f32x4){0.f,0.f,0.f,0.f};
}
__device__ __forceinline__ void zero_acc(f32x4 (&acc)[4][4]){
  #pragma unroll
  for(int a=0;a<4;++a)
    #pragma unroll
    for(int b=0;b<4;++b)
      acc[a][b] = (f32x4){0.f,0.f,0.f,0.f};
}

// ---------------- k_layers phase helpers ----------------
// LN(h tile m0) -> z bf16 into A (8 thr/row)
__device__ __forceinline__ void ph_ln(const unsigned short* __restrict__ h_g, int m0,
    char* A, const float* __restrict__ lg, const float* __restrict__ lb,
    int rA, int cAh)
{
  const unsigned short* src = h_g + (size_t)(m0 + rA)*DMODEL + cAh;
  short8 hv[4];
  #pragma unroll
  for(int i = 0; i < 4; ++i) hv[i] = *(const short8*)(src + i*8);
  float sm = 0.f, sq = 0.f;
  #pragma unroll
  for(int i = 0; i < 4; ++i)
    #pragma unroll
    for(int j = 0; j < 8; ++j){
      float v = bf2f((unsigned short)hv[i][j]); sm += v; sq += v*v;
    }
  sm += __shfl_xor(sm, 1); sm += __shfl_xor(sm, 2); sm += __shfl_xor(sm, 4);
  sq += __shfl_xor(sq, 1); sq += __shfl_xor(sq, 2); sq += __shfl_xor(sq, 4);
  const float mu = sm * (1.f/256.f);
  const float rstd = rsqrtf(sq * (1.f/256.f) - mu*mu + 1e-5f);
  #pragma unroll
  for(int i = 0; i < 4; ++i){
    float z[8];
    #pragma unroll
    for(int j = 0; j < 8; ++j){
      const int c = cAh + i*8 + j;
      z[j] = (bf2f((unsigned short)hv[i][j])-mu)*rstd*lg[c] + lb[c];
    }
    u32x4 zz;
    zz[0] = pk_bf16(z[0],z[1]); zz[1] = pk_bf16(z[2],z[3]);
    zz[2] = pk_bf16(z[4],z[5]); zz[3] = pk_bf16(z[6],z[7]);
    *(u32x4*)(A + swzA(rA, cAh*2 + i*16)) = zz;
  }
}

// gate GEMM(A) -> xg=silu -> S (b64 contiguous writes)
__device__ __forceinline__ void ph_gate(const unsigned short* __restrict__ gw,
    const char* A, char* S, const float* __restrict__ gb_,
    int lane, int c0w)
{
  f32x4 acc[4][2]; zero_acc2(acc);
  gemm_w8(gw, A, acc, lane, c0w);
  const int nrow = lane & 15;
  const int mc4  = (lane >> 4) * 4;
  #pragma unroll
  for(int fc = 0; fc < 2; ++fc){
    const int colb = c0w + fc*16 + mc4;
    const f32x4 gb4 = *(const f32x4*)(gb_ + colb);
    #pragma unroll
    for(int fr = 0; fr < 4; ++fr){
      const int row = fr*16 + nrow;
      float v0 = silu_f(acc[fr][fc][0] + gb4[0]), v1 = silu_f(acc[fr][fc][1] + gb4[1]);
      float v2 = silu_f(acc[fr][fc][2] + gb4[2]), v3 = silu_f(acc[fr][fc][3] + gb4[3]);
      u32x2 w; w[0] = pk_bf16(v0, v1); w[1] = pk_bf16(v2, v3);
      *(u32x2*)(S + swzA(row, colb*2)) = w;
    }
  }
}

// sp GEMM(S=xg) -> s=+sp_b -> A (b64 writes)
__device__ __forceinline__ void ph_sp(const unsigned short* __restrict__ spw,
    const char* S, char* A, const float* __restrict__ sb_,
    int lane, int c0w)
{
  f32x4 acc[4][2]; zero_acc2(acc);
  gemm_w8(spw, S, acc, lane, c0w);
  const int nrow = lane & 15;
  const int mc4  = (lane >> 4) * 4;
  #pragma unroll
  for(int fc = 0; fc < 2; ++fc){
    const int colb = c0w + fc*16 + mc4;
    const f32x4 sb4 = *(const f32x4*)(sb_ + colb);
    #pragma unroll
    for(int fr = 0; fr < 4; ++fr){
      const int row = fr*16 + nrow;
      u32x2 w;
      w[0] = pk_bf16(acc[fr][fc][0] + sb4[0], acc[fr][fc][1] + sb4[1]);
      w[1] = pk_bf16(acc[fr][fc][2] + sb4[2], acc[fr][fc][3] + sb4[3]);
      *(u32x2*)(A + swzA(row, colb*2)) = w;
    }
  }
}

// scan in A (thread=channel, tid<256), chunked 16
__device__ __forceinline__ void ph_scan(char* A, float& st, float dc, int tid)
{
  if(tid < 256){
    #pragma unroll
    for(int c4 = 0; c4 < 4; ++c4){
      const int base = c4*16;
      float v[16];
      #pragma unroll
      for(int j = 0; j < 16; ++j)
        v[j] = bf2f(*(const unsigned short*)(A + swzA(base+j, tid*2)));
      #pragma unroll
      for(int j = 0; j < 16; ++j){ st = st*dc + v[j]; v[j] = st; }
      #pragma unroll
      for(int j = 0; j < 8; ++j){
        unsigned p = pk_bf16(v[2*j], v[2*j+1]);
        *(unsigned short*)(A + swzA(base+2*j,   tid*2)) = (unsigned short)p;
        *(unsigned short*)(A + swzA(base+2*j+1, tid*2)) = (unsigned short)(p >> 16);
      }
    }
  }
}

// spT GEMM(A=states) -> y = acc + D*xg, IN-PLACE in S (b64 read + b64 write)
__device__ __forceinline__ void ph_spt_y(const unsigned short* __restrict__ spT,
    const char* A, char* S, const float* __restrict__ Dv_,
    int lane, int c0w)
{
  f32x4 acc[4][2]; zero_acc2(acc);
  gemm_w8(spT, A, acc, lane, c0w);
  const int nrow = lane & 15;
  const int mc4  = (lane >> 4) * 4;
  #pragma unroll
  for(int fc = 0; fc < 2; ++fc){
    const int colb = c0w + fc*16 + mc4;
    const f32x4 D4 = *(const f32x4*)(Dv_ + colb);
    #pragma unroll
    for(int fr = 0; fr < 4; ++fr){
      const int row = fr*16 + nrow;
      const unsigned a = swzA(row, colb*2);
      u32x2 xg = *(const u32x2*)(S + a);
      float y0 = acc[fr][fc][0] + D4[0]*bf2f((unsigned short)xg[0]);
      float y1 = acc[fr][fc][1] + D4[1]*bf2f((unsigned short)(xg[0] >> 16));
      float y2 = acc[fr][fc][2] + D4[2]*bf2f((unsigned short)xg[1]);
      float y3 = acc[fr][fc][3] + D4[3]*bf2f((unsigned short)(xg[1] >> 16));
      u32x2 w; w[0] = pk_bf16(y0, y1); w[1] = pk_bf16(y2, y3);
      *(u32x2*)(S + a) = w;
    }
  }
}

// op GEMM(S=y) -> +op_b -> A (b64 writes) -> wave-local h-RMW (own 32 cols)
__device__ __forceinline__ void ph_op_rmw(const unsigned short* __restrict__ opw,
    const char* S, char* A, const float* __restrict__ ob_,
    unsigned short* __restrict__ h_g, int m0,
    int lane, int c0w)
{
  f32x4 acc[4][2]; zero_acc2(acc);
  gemm_w8(opw, S, acc, lane, c0w);
  const int nrow = lane & 15;
  const int mc4  = (lane >> 4) * 4;
  #pragma unroll
  for(int fc = 0; fc < 2; ++fc){
    const int colb = c0w + fc*16 + mc4;
    const f32x4 ob4 = *(const f32x4*)(ob_ + colb);
    #pragma unroll
    for(int fr = 0; fr < 4; ++fr){
      const int row = fr*16 + nrow;
      u32x2 w;
      w[0] = pk_bf16(acc[fr][fc][0] + ob4[0], acc[fr][fc][1] + ob4[1]);
      w[1] = pk_bf16(acc[fr][fc][2] + ob4[2], acc[fr][fc][3] + ob4[3]);
      *(u32x2*)(A + swzA(row, colb*2)) = w;
    }
  }
  // wave-local RMW (v12-proven): own 32 cols, 64B sector chunks per row
  {
    char* hb = (char*)(h_g + (size_t)m0*DMODEL);
    const int cl = lane & 3;
    const int rbase = lane >> 2;
    #pragma unroll
    for(int p = 0; p < 4; ++p){
      const int row = p*16 + rbase;
      const unsigned gof = (unsigned)(row*512 + c0w*2 + cl*16);
      short8 a = *(const short8*)(A + swzA(row, c0w*2 + cl*16));
      short8 hv = *(const short8*)(hb + gof);
      u32x4 o;
      #pragma unroll
      for(int j = 0; j < 4; ++j){
        float s0 = bf2f((unsigned short)a[2*j])   + bf2f((unsigned short)hv[2*j]);
        float s1 = bf2f((unsigned short)a[2*j+1]) + bf2f((unsigned short)hv[2*j+1]);
        o[j] = pk_bf16(s0, s1);
      }
      *(u32x4*)(hb + gof) = o;
    }
  }
}

// LDS-staged GEMM (k_in_proj / k_out only, proven, 256 thr)
template<int KCH>
__device__ __forceinline__ void gemm_64x256(const unsigned short* __restrict__ wb,
                                            char* As, char* Bs,
                                            f32x4 (&acc)[4][4], int tid)
{
  const int lane = tid & 63;
  const int c0   = (tid >> 6) * 64;
  const int lr   = lane & 15;
  const int lk16 = (lane >> 4) * 16;
  #pragma unroll
  for(int kc = 0; kc < KCH; ++kc){
    __syncthreads();
    {
      const unsigned short* src = wb + (size_t)tid * (KCH*64) + kc*64;
      #pragma unroll
      for(int i = 0; i < 8; ++i){
        short8 v = *(const short8*)(src + i*8);
        *(short8*)(Bs + swzB(tid, i*16)) = v;
      }
    }
    __syncthreads();
    #pragma unroll
    for(int t2 = 0; t2 < 2; ++t2){
      bf16x8 af[4], bfr[4];
      #pragma unroll
      for(int fr = 0; fr < 4; ++fr)
        af[fr] = *(const bf16x8*)(As + swzA(fr*16 + lr, kc*128 + t2*64 + lk16));
      #pragma unroll
      for(int fc = 0; fc < 4; ++fc)
        bfr[fc] = *(const bf16x8*)(Bs + swzB(c0 + fc*16 + lr, t2*64 + lk16));
      #pragma unroll
      for(int fr = 0; fr < 4; ++fr)
        #pragma unroll
        for(int fc = 0; fc < 4; ++fc)
          acc[fr][fc] = __builtin_amdgcn_mfma_f32_16x16x32_bf16(af[fr], bfr[fc], acc[fr][fc], 0, 0, 0);
    }
  }
}

// ---------------- prep kernels ----------------
__global__ void k_cvt(const float* __restrict__ s, unsigned short* __restrict__ d, int n){
  int i = blockIdx.x*256 + threadIdx.x;
  if(i < n) d[i] = f2bf(s[i]);
}
__global__ void k_cvt_inw(const float* __restrict__ w, unsigned short* __restrict__ d){
  int i = blockIdx.x*256 + threadIdx.x;
  int n = i >> 7, f = i & 127;
  d[i] = (f < 96) ? f2bf(w[n*96 + f]) : (unsigned short)0;
}
__global__ void k_spT(const float* __restrict__ spw, unsigned short* __restrict__ d){
  int l = blockIdx.y;
  int i = blockIdx.x*256 + threadIdx.x;
  int dd = i >> 8, ss = i & 255;
  d[l*65536 + i] = f2bf(spw[l*65536 + ss*256 + dd]);
}
__global__ void k_decay(const float* __restrict__ A_log, float* __restrict__ decay){
  __shared__ float red[4];
  const int b = blockIdx.x;
  const int tid = threadIdx.x;
  float v = expf(A_log[(size_t)b*256 + tid]);
  #pragma unroll
  for(int o = 32; o >= 1; o >>= 1) v += __shfl_xor(v, o);
  if((tid & 63) == 0) red[tid >> 6] = v;
  __syncthreads();
  if(tid == 0){
    float s = red[0] + red[1] + red[2] + red[3];
    decay[b] = expf(-s * (1.f/256.f));
  }
}

// ---------------- h = gelu(LN(x @ in_w^T + in_b)) -> bf16 (proven) ----------------
__global__ __launch_bounds__(256) void k_in_proj(
    const float* __restrict__ x_g,
    const unsigned short* __restrict__ in_wb,
    const float* __restrict__ in_b,
    const float* __restrict__ ln_gv, const float* __restrict__ ln_bv,
    unsigned short* __restrict__ h_g)
{
  __shared__ char smem[65536];
  char* As = smem; char* Bs = smem + 32768;
  const int tid = threadIdx.x;
  const int m0 = blockIdx.x * 64;
  const int lane = tid & 63, c0w = (tid>>6)*64, lr = lane & 15, rb = (lane>>4)*4;
  {
    const int r = tid >> 2, cq = tid & 3;
    const float* src = x_g + (size_t)(m0 + r)*FIN + cq*24;
    unsigned short tmp[24] __attribute__((aligned(16)));
    #pragma unroll
    for(int i = 0; i < 6; ++i){
      float4 v = *(const float4*)(src + i*4);
      tmp[4*i]=f2bf(v.x); tmp[4*i+1]=f2bf(v.y); tmp[4*i+2]=f2bf(v.z); tmp[4*i+3]=f2bf(v.w);
    }
    #pragma unroll
    for(int i = 0; i < 3; ++i)
      *(short8*)(As + swzA(r, cq*48 + i*16)) = *(const short8*)(tmp + i*8);
    if(cq == 3){
      short8 z8 = {0,0,0,0,0,0,0,0};
      #pragma unroll
      for(int i = 0; i < 4; ++i)
        *(short8*)(As + swzA(r, 192 + i*16)) = z8;
    }
  }
  f32x4 acc[4][4]; zero_acc(acc);
  gemm_64x256<2>(in_wb, As, Bs, acc, tid);
  __syncthreads();
  #pragma unroll
  for(int fc = 0; fc < 4; ++fc){
    const int col = c0w + fc*16 + lr;
    const float bb = in_b[col];
    #pragma unroll
    for(int fr = 0; fr < 4; ++fr)
      #pragma unroll
      for(int rg = 0; rg < 4; ++rg){
        const int row = fr*16 + rb + rg;
        *(float*)(smem + (((unsigned)(row*1024 + col*4)) ^ ((row&7)<<4))) = acc[fr][fc][rg] + bb;
      }
  }
  __syncthreads();
  {
    const int r = tid >> 2, c0 = (tid & 3) * 64;
    float vals[64]; float sm = 0.f, sq = 0.f;
    #pragma unroll
    for(int i = 0; i < 16; ++i){
      float4 v = *(const float4*)(smem + (((unsigned)(r*1024 + (c0 + i*4)*4)) ^ ((r&7)<<4)));
      vals[4*i]=v.x; vals[4*i+1]=v.y; vals[4*i+2]=v.z; vals[4*i+3]=v.w;
    }
    #pragma unroll
    for(int i = 0; i < 64; ++i){ sm += vals[i]; sq += vals[i]*vals[i]; }
    sm += __shfl_xor(sm, 1); sm += __shfl_xor(sm, 2);
    sq += __shfl_xor(sq, 1); sq += __shfl_xor(sq, 2);
    const float mu = sm * (1.f/256.f);
    const float rstd = rsqrtf(sq * (1.f/256.f) - mu*mu + 1e-5f);
    unsigned short* dst = h_g + (size_t)(m0 + r)*DMODEL + c0;
    #pragma unroll
    for(int i = 0; i < 8; ++i){
      float g[8];
      #pragma unroll
      for(int j = 0; j < 8; ++j){
        const int c = c0 + i*8 + j;
        g[j] = gelu_f((vals[i*8+j]-mu)*rstd*ln_gv[c] + ln_bv[c]);
      }
      u32x4 o;
      o[0] = pk_bf16(g[0],g[1]); o[1] = pk_bf16(g[2],g[3]);
      o[2] = pk_bf16(g[4],g[5]); o[3] = pk_bf16(g[6],g[7]);
      *(u32x4*)(dst + i*8) = o;
    }
  }
}

// ---------------- BOTH layers, two-tile pipelined: block = sequence, 512 thr ----------------
__global__ __launch_bounds__(512,2) void k_layers(
    unsigned short* __restrict__ h_g,
    const unsigned short* __restrict__ gate_w0,
    const unsigned short* __restrict__ sp_w0,
    const unsigned short* __restrict__ spT_w0,
    const unsigned short* __restrict__ op_w0,
    const float* __restrict__ ln_g0, const float* __restrict__ ln_b0,
    const float* __restrict__ gate_b0, const float* __restrict__ sp_b0,
    const float* __restrict__ decay0, const float* __restrict__ D0,
    const float* __restrict__ op_b0)
{
  __shared__ char As0[32768];
  __shared__ char Ss0[32768];
  __shared__ char As1[32768];
  __shared__ char Ss1[32768];
  const int tid = threadIdx.x;
  const int n = blockIdx.x;
  const int lane = tid & 63;
  const int c0w = (tid >> 6) * 32;            // wave -> 32 output cols
  const int rA = tid >> 3, cAh = (tid & 7) * 32;   // LN: 8 thr/row
  float st = 0.f;                              // scan state across layers

  #pragma unroll 1
  for(int l = 0; l < 2; ++l){
    const unsigned short* gw  = gate_w0 + l*65536;
    const unsigned short* spw = sp_w0   + l*65536;
    const unsigned short* spT = spT_w0  + l*65536;
    const unsigned short* opw = op_w0   + l*65536;
    const float* lg  = ln_g0   + l*256;
    const float* lb  = ln_b0   + l*256;
    const float* gb_ = gate_b0 + l*256;
    const float* sb_ = sp_b0   + l*256;
    const float* Dv_ = D0      + l*256;
    const float* ob_ = op_b0   + l*256;
    const float dc = decay0[l*256 + (tid & 255)];
    const int mL = n*KSEQ;

    // prologue: tile 0 front phases on buffer pair 0
    ph_ln(h_g, mL, As0, lg, lb, rA, cAh);
    __syncthreads();
    ph_gate(gw, As0, Ss0, gb_, lane, c0w);
    __syncthreads();
    ph_sp(spw, Ss0, As0, sb_, lane, c0w);
    __syncthreads();

    #pragma unroll 1
    for(int kb = 0; kb < 8; ++kb){
      char* Ab = (kb & 1) ? As1 : As0;
      char* Sb = (kb & 1) ? Ss1 : Ss0;
      char* Af = (kb & 1) ? As0 : As1;
      char* Sf = (kb & 1) ? Ss0 : Ss1;
      const int m0 = mL + kb*64;
      // SP1: front LN (global loads early) || back scan (serial LDS chain)
      if(kb < 7) ph_ln(h_g, m0 + 64, Af, lg, lb, rA, cAh);
      ph_scan(Ab, st, dc, tid);
      __syncthreads();
      // SP2: back spT + y-epi (Ss in place) || front gate + xg-epi
      ph_spt_y(spT, Ab, Sb, Dv_, lane, c0w);
      if(kb < 7) ph_gate(gw, Af, Sf, gb_, lane, c0w);
      __syncthreads();
      // SP3: back op + op-epi + h-RMW || front sp + s-epi
      ph_op_rmw(opw, Sb, Ab, ob_, h_g, m0, lane, c0w);
      if(kb < 7) ph_sp(spw, Sf, Af, sb_, lane, c0w);
      __syncthreads();
    }
  }
}

// ---------------- out = gelu(LN(h[:,511,:] @ out_w^T + out_b)) (proven) ----------------
__global__ __launch_bounds__(256) void k_out(
    const unsigned short* __restrict__ h_g,
    const unsigned short* __restrict__ out_wb,
    const float* __restrict__ out_bv,
    const float* __restrict__ ln_gv, const float* __restrict__ ln_bv,
    float* __restrict__ out_g)
{
  __shared__ char smem[65536];
  char* As = smem; char* Bs = smem + 32768;
  const int tid = threadIdx.x;
  const int r0 = blockIdx.x * 64;
  const int lane = tid & 63, c0w = (tid>>6)*64, lr = lane & 15, rb = (lane>>4)*4;
  {
    const int r = tid >> 2, c0 = (tid & 3) * 64;
    const unsigned short* src = h_g + ((size_t)(r0 + r)*KSEQ + (KSEQ-1))*DMODEL + c0;
    #pragma unroll
    for(int i = 0; i < 8; ++i){
      short8 v = *(const short8*)(src + i*8);
      *(short8*)(As + swzA(r, c0*2 + i*16)) = v;
    }
  }
  f32x4 acc[4][4]; zero_acc(acc);
  gemm_64x256<4>(out_wb, As, Bs, acc, tid);
  __syncthreads();
  #pragma unroll
  for(int fc = 0; fc < 4; ++fc){
    const int col = c0w + fc*16 + lr;
    const float bb = out_bv[col];
    #pragma unroll
    for(int fr = 0; fr < 4; ++fr)
      #pragma unroll
      for(int rg = 0; rg < 4; ++rg){
        const int row = fr*16 + rb + rg;
        *(float*)(smem + (((unsigned)(row*1024 + col*4)) ^ ((row&7)<<4))) = acc[fr][fc][rg] + bb;
      }
  }
  __syncthreads();
  {
    const int r = tid >> 2, c0 = (tid & 3) * 64;
    float vals[64]; float sm = 0.f, sq = 0.f;
    #pragma unroll
    for(int i = 0; i < 16; ++i){
      float4 v = *(const float4*)(smem + (((unsigned)(r*1024 + (c0 + i*4)*4)) ^ ((r&7)<<4)));
      vals[4*i]=v.x; vals[4*i+1]=v.y; vals[4*i+2]=v.z; vals[4*i+3]=v.w;
    }
    #pragma unroll
    for(int i = 0; i < 64; ++i){ sm += vals[i]; sq += vals[i]*vals[i]; }
    sm += __shfl_xor(sm, 1); sm += __shfl_xor(sm, 2);
    sq += __shfl_xor(sq, 1); sq += __shfl_xor(sq, 2);
    const float mu = sm * (1.f/256.f);
    const float rstd = rsqrtf(sq * (1.f/256.f) - mu*mu + 1e-5f);
    float* dst = out_g + (size_t)(r0 + r)*DMODEL + c0;
    #pragma unroll
    for(int i = 0; i < 16; ++i){
      float4 o;
      o.x = gelu_f((vals[4*i+0]-mu)*rstd*ln_gv[c0+i*4+0] + ln_bv[c0+i*4+0]);
      o.y = gelu_f((vals[4*i+1]-mu)*rstd*ln_gv[c0+i*4+1] + ln_bv[c0+i*4+1]);
      o.z = gelu_f((vals[4*i+2]-mu)*rstd*ln_gv[c0+i*4+2] + ln_bv[c0+i*4+2]);
      o.w = gelu_f((vals[4*i+3]-mu)*rstd*ln_gv[c0+i*4+3] + ln_bv[c0+i*4+3]);
      *(float4*)(dst + i*4) = o;
    }
  }
}

extern "C" void kernel_launch(void* const* d_in, const int* in_sizes, int n_in,
                              void* d_out, int out_size, void* d_ws, size_t ws_size,
                              hipStream_t stream) {
  (void)in_sizes; (void)n_in; (void)out_size; (void)ws_size;
  const float* x        = (const float*)d_in[0];
  const float* in_w     = (const float*)d_in[1];
  const float* in_b     = (const float*)d_in[2];
  const float* in_ln_g  = (const float*)d_in[3];
  const float* in_ln_b  = (const float*)d_in[4];
  const float* ln_g     = (const float*)d_in[5];
  const float* ln_b     = (const float*)d_in[6];
  const float* gate_w   = (const float*)d_in[7];
  const float* gate_b   = (const float*)d_in[8];
  const float* sp_w     = (const float*)d_in[9];
  const float* sp_b     = (const float*)d_in[10];
  const float* op_w     = (const float*)d_in[11];
  const float* op_b     = (const float*)d_in[12];
  const float* A_log    = (const float*)d_in[13];
  const float* Dp       = (const float*)d_in[14];
  const float* out_w    = (const float*)d_in[15];
  const float* out_b    = (const float*)d_in[16];
  const float* out_ln_g = (const float*)d_in[17];
  const float* out_ln_b = (const float*)d_in[18];

  char* ws = (char*)d_ws;
  // ~133.7 MiB workspace (proven budget)
  unsigned short* h_g       = (unsigned short*)(ws + 0);           // 128 MiB
  float*          decay     = (float*)(ws + 134217728);            // 2 KiB
  unsigned short* wbase     = (unsigned short*)(ws + 134219776);   // ~1.2 MiB
  unsigned short* in_wb  = wbase;               // 32768
  unsigned short* gate_wb= in_wb  + 32768;      // 2*65536
  unsigned short* sp_wb  = gate_wb+ 131072;
  unsigned short* sp_wTb = sp_wb  + 131072;
  unsigned short* op_wb  = sp_wTb + 131072;
  unsigned short* out_wb = op_wb  + 131072;     // 65536

  // prep
  k_cvt_inw<<<128, 256, 0, stream>>>(in_w, in_wb);
  k_cvt<<<512, 256, 0, stream>>>(gate_w, gate_wb, 131072);
  k_cvt<<<512, 256, 0, stream>>>(sp_w,   sp_wb,   131072);
  k_cvt<<<512, 256, 0, stream>>>(op_w,   op_wb,   131072);
  k_cvt<<<256, 256, 0, stream>>>(out_w,  out_wb,  65536);
  k_spT<<<dim3(256,2), 256, 0, stream>>>(sp_w, sp_wTb);
  k_decay<<<512, 256, 0, stream>>>(A_log, decay);

  // pipeline
  k_in_proj<<<MTOT/64, 256, 0, stream>>>(x, in_wb, in_b, in_ln_g, in_ln_b, h_g);
  k_layers<<<NSEQ, 512, 0, stream>>>(h_g, gate_wb, sp_wb, sp_wTb, op_wb,
      ln_g, ln_b, gate_b, sp_b, decay, Dp, op_b);
  k_out<<<NSEQ/64, 256, 0, stream>>>(h_g, out_wb, out_b, out_ln_g, out_ln_b, (float*)d_out);
}

// Round 17
// 965.826 us; speedup vs baseline: 1.4220x; 1.0027x over previous
//
#include <hip/hip_runtime.h>
#include <hip/hip_bf16.h>

// MambaEncoder on MI355X — v17: v16 (operand-swapped two-tile pipeline, 968us)
// + lgkmcnt-only barriers (barx) INSIDE layers: all in-layer cross-wave deps
// are LDS; global h-RMW is only consumed across the layer boundary, where one
// full __syncthreads (vmcnt drain) remains. Global B-panel / LN loads now stay
// in flight across superphase barriers. Bit-identical numerics. ws ~133.7MiB.

typedef __attribute__((ext_vector_type(8))) __bf16 bf16x8;
typedef __attribute__((ext_vector_type(8))) short short8;
typedef __attribute__((ext_vector_type(4))) float f32x4;
typedef __attribute__((ext_vector_type(4))) unsigned u32x4;
typedef __attribute__((ext_vector_type(2))) unsigned u32x2;

#define NSEQ 512
#define KSEQ 512
#define FIN 96
#define DMODEL 256
#define MTOT (NSEQ*KSEQ)

__device__ __forceinline__ unsigned short f2bf(float f){
  union { float f; unsigned u; } v; v.f = f;
  unsigned r = (v.u + 0x7FFFu + ((v.u >> 16) & 1u)) >> 16;
  return (unsigned short)r;
}
__device__ __forceinline__ float bf2f(unsigned short b){
  union { unsigned u; float f; } v; v.u = ((unsigned)b) << 16; return v.f;
}
__device__ __forceinline__ unsigned pk_bf16(float lo, float hi){
  unsigned r;
  asm("v_cvt_pk_bf16_f32 %0, %1, %2" : "=v"(r) : "v"(lo), "v"(hi));
  return r;
}
__device__ __forceinline__ float gelu_f(float x){
  return 0.5f * x * (1.0f + erff(x * 0.70710678118654752440f));
}
__device__ __forceinline__ float silu_f(float x){
  return x / (1.0f + __expf(-x));
}
// LDS-only barrier: in-layer cross-wave deps are LDS; global loads stay in flight.
__device__ __forceinline__ void barx(){
  asm volatile("s_waitcnt lgkmcnt(0)" ::: "memory");
  __builtin_amdgcn_s_barrier();
}
__device__ __forceinline__ unsigned swzA(int row, int kbyte){   // [64][256] bf16, 512B stride
  return ((unsigned)(row*512 + kbyte)) ^ (unsigned)((row & 7) << 4);
}
__device__ __forceinline__ unsigned swzB(int n, int kbyte){     // [256][64] bf16
  return ((unsigned)(n*128 + kbyte)) ^ (unsigned)((n & 7) << 4);
}

// 8-wave col-split GEMM, OPERAND-SWAPPED: acc[fr][fc][reg] ->
//   actrow = fr*16 + (lane&15), wcol = c0 + fc*16 + (lane>>4)*4 + reg.
// B direct from global (cache-resident), 4-deep chunk prefetch ring.
__device__ __forceinline__ void gemm_w8(const unsigned short* __restrict__ wb,
                                        const char* As, f32x4 (&acc)[4][2],
                                        int lane, int c0)
{
  const int lr  = lane & 15;
  const int lk8 = (lane >> 4) * 8;
  const unsigned short* bp = wb + (size_t)(c0 + lr)*256 + lk8;   // +fc*4096 +kc*32
  bf16x8 bb[4][2];
  #pragma unroll
  for(int p = 0; p < 4; ++p)
    #pragma unroll
    for(int fc = 0; fc < 2; ++fc)
      bb[p][fc] = *(const bf16x8*)(bp + fc*4096 + p*32);
  #pragma unroll
  for(int kc = 0; kc < 8; ++kc){
    bf16x8 af[4];
    #pragma unroll
    for(int fr = 0; fr < 4; ++fr)
      af[fr] = *(const bf16x8*)(As + swzA(fr*16 + lr, kc*64 + lk8*2));
    #pragma unroll
    for(int fr = 0; fr < 4; ++fr)
      #pragma unroll
      for(int fc = 0; fc < 2; ++fc)
        acc[fr][fc] = __builtin_amdgcn_mfma_f32_16x16x32_bf16(bb[kc&3][fc], af[fr], acc[fr][fc], 0, 0, 0);
    if(kc < 4){
      #pragma unroll
      for(int fc = 0; fc < 2; ++fc)
        bb[kc&3][fc] = *(const bf16x8*)(bp + fc*4096 + (kc+4)*32);
    }
  }
}

__device__ __forceinline__ void zero_acc2(f32x4 (&acc)[4][2]){
  #pragma unroll
  for(int a=0;a<4;++a)
    #pragma unroll
    for(int b=0;b<2;++b)
      acc[a][b] = (f32x4){0.f,0.f,0.f,0.f};
}
__device__ __forceinline__ void zero_acc(f32x4 (&acc)[4][4]){
  #pragma unroll
  for(int a=0;a<4;++a)
    #pragma unroll
    for(int b=0;b<4;++b)
      acc[a][b] = (f32x4){0.f,0.f,0.f,0.f};
}

// ---------------- k_layers phase helpers (v16-proven) ----------------
__device__ __forceinline__ void ph_ln(const unsigned short* __restrict__ h_g, int m0,
    char* A, const float* __restrict__ lg, const float* __restrict__ lb,
    int rA, int cAh)
{
  const unsigned short* src = h_g + (size_t)(m0 + rA)*DMODEL + cAh;
  short8 hv[4];
  #pragma unroll
  for(int i = 0; i < 4; ++i) hv[i] = *(const short8*)(src + i*8);
  float sm = 0.f, sq = 0.f;
  #pragma unroll
  for(int i = 0; i < 4; ++i)
    #pragma unroll
    for(int j = 0; j < 8; ++j){
      float v = bf2f((unsigned short)hv[i][j]); sm += v; sq += v*v;
    }
  sm += __shfl_xor(sm, 1); sm += __shfl_xor(sm, 2); sm += __shfl_xor(sm, 4);
  sq += __shfl_xor(sq, 1); sq += __shfl_xor(sq, 2); sq += __shfl_xor(sq, 4);
  const float mu = sm * (1.f/256.f);
  const float rstd = rsqrtf(sq * (1.f/256.f) - mu*mu + 1e-5f);
  #pragma unroll
  for(int i = 0; i < 4; ++i){
    float z[8];
    #pragma unroll
    for(int j = 0; j < 8; ++j){
      const int c = cAh + i*8 + j;
      z[j] = (bf2f((unsigned short)hv[i][j])-mu)*rstd*lg[c] + lb[c];
    }
    u32x4 zz;
    zz[0] = pk_bf16(z[0],z[1]); zz[1] = pk_bf16(z[2],z[3]);
    zz[2] = pk_bf16(z[4],z[5]); zz[3] = pk_bf16(z[6],z[7]);
    *(u32x4*)(A + swzA(rA, cAh*2 + i*16)) = zz;
  }
}

__device__ __forceinline__ void ph_gate(const unsigned short* __restrict__ gw,
    const char* A, char* S, const float* __restrict__ gb_,
    int lane, int c0w)
{
  f32x4 acc[4][2]; zero_acc2(acc);
  gemm_w8(gw, A, acc, lane, c0w);
  const int nrow = lane & 15;
  const int mc4  = (lane >> 4) * 4;
  #pragma unroll
  for(int fc = 0; fc < 2; ++fc){
    const int colb = c0w + fc*16 + mc4;
    const f32x4 gb4 = *(const f32x4*)(gb_ + colb);
    #pragma unroll
    for(int fr = 0; fr < 4; ++fr){
      const int row = fr*16 + nrow;
      float v0 = silu_f(acc[fr][fc][0] + gb4[0]), v1 = silu_f(acc[fr][fc][1] + gb4[1]);
      float v2 = silu_f(acc[fr][fc][2] + gb4[2]), v3 = silu_f(acc[fr][fc][3] + gb4[3]);
      u32x2 w; w[0] = pk_bf16(v0, v1); w[1] = pk_bf16(v2, v3);
      *(u32x2*)(S + swzA(row, colb*2)) = w;
    }
  }
}

__device__ __forceinline__ void ph_sp(const unsigned short* __restrict__ spw,
    const char* S, char* A, const float* __restrict__ sb_,
    int lane, int c0w)
{
  f32x4 acc[4][2]; zero_acc2(acc);
  gemm_w8(spw, S, acc, lane, c0w);
  const int nrow = lane & 15;
  const int mc4  = (lane >> 4) * 4;
  #pragma unroll
  for(int fc = 0; fc < 2; ++fc){
    const int colb = c0w + fc*16 + mc4;
    const f32x4 sb4 = *(const f32x4*)(sb_ + colb);
    #pragma unroll
    for(int fr = 0; fr < 4; ++fr){
      const int row = fr*16 + nrow;
      u32x2 w;
      w[0] = pk_bf16(acc[fr][fc][0] + sb4[0], acc[fr][fc][1] + sb4[1]);
      w[1] = pk_bf16(acc[fr][fc][2] + sb4[2], acc[fr][fc][3] + sb4[3]);
      *(u32x2*)(A + swzA(row, colb*2)) = w;
    }
  }
}

__device__ __forceinline__ void ph_scan(char* A, float& st, float dc, int tid)
{
  if(tid < 256){
    #pragma unroll
    for(int c4 = 0; c4 < 4; ++c4){
      const int base = c4*16;
      float v[16];
      #pragma unroll
      for(int j = 0; j < 16; ++j)
        v[j] = bf2f(*(const unsigned short*)(A + swzA(base+j, tid*2)));
      #pragma unroll
      for(int j = 0; j < 16; ++j){ st = st*dc + v[j]; v[j] = st; }
      #pragma unroll
      for(int j = 0; j < 8; ++j){
        unsigned p = pk_bf16(v[2*j], v[2*j+1]);
        *(unsigned short*)(A + swzA(base+2*j,   tid*2)) = (unsigned short)p;
        *(unsigned short*)(A + swzA(base+2*j+1, tid*2)) = (unsigned short)(p >> 16);
      }
    }
  }
}

__device__ __forceinline__ void ph_spt_y(const unsigned short* __restrict__ spT,
    const char* A, char* S, const float* __restrict__ Dv_,
    int lane, int c0w)
{
  f32x4 acc[4][2]; zero_acc2(acc);
  gemm_w8(spT, A, acc, lane, c0w);
  const int nrow = lane & 15;
  const int mc4  = (lane >> 4) * 4;
  #pragma unroll
  for(int fc = 0; fc < 2; ++fc){
    const int colb = c0w + fc*16 + mc4;
    const f32x4 D4 = *(const f32x4*)(Dv_ + colb);
    #pragma unroll
    for(int fr = 0; fr < 4; ++fr){
      const int row = fr*16 + nrow;
      const unsigned a = swzA(row, colb*2);
      u32x2 xg = *(const u32x2*)(S + a);
      float y0 = acc[fr][fc][0] + D4[0]*bf2f((unsigned short)xg[0]);
      float y1 = acc[fr][fc][1] + D4[1]*bf2f((unsigned short)(xg[0] >> 16));
      float y2 = acc[fr][fc][2] + D4[2]*bf2f((unsigned short)xg[1]);
      float y3 = acc[fr][fc][3] + D4[3]*bf2f((unsigned short)(xg[1] >> 16));
      u32x2 w; w[0] = pk_bf16(y0, y1); w[1] = pk_bf16(y2, y3);
      *(u32x2*)(S + a) = w;
    }
  }
}

__device__ __forceinline__ void ph_op_rmw(const unsigned short* __restrict__ opw,
    const char* S, char* A, const float* __restrict__ ob_,
    unsigned short* __restrict__ h_g, int m0,
    int lane, int c0w)
{
  f32x4 acc[4][2]; zero_acc2(acc);
  gemm_w8(opw, S, acc, lane, c0w);
  const int nrow = lane & 15;
  const int mc4  = (lane >> 4) * 4;
  #pragma unroll
  for(int fc = 0; fc < 2; ++fc){
    const int colb = c0w + fc*16 + mc4;
    const f32x4 ob4 = *(const f32x4*)(ob_ + colb);
    #pragma unroll
    for(int fr = 0; fr < 4; ++fr){
      const int row = fr*16 + nrow;
      u32x2 w;
      w[0] = pk_bf16(acc[fr][fc][0] + ob4[0], acc[fr][fc][1] + ob4[1]);
      w[1] = pk_bf16(acc[fr][fc][2] + ob4[2], acc[fr][fc][3] + ob4[3]);
      *(u32x2*)(A + swzA(row, colb*2)) = w;
    }
  }
  // wave-local RMW: own 32 cols, 64B sector chunks per row
  {
    char* hb = (char*)(h_g + (size_t)m0*DMODEL);
    const int cl = lane & 3;
    const int rbase = lane >> 2;
    #pragma unroll
    for(int p = 0; p < 4; ++p){
      const int row = p*16 + rbase;
      const unsigned gof = (unsigned)(row*512 + c0w*2 + cl*16);
      short8 a = *(const short8*)(A + swzA(row, c0w*2 + cl*16));
      short8 hv = *(const short8*)(hb + gof);
      u32x4 o;
      #pragma unroll
      for(int j = 0; j < 4; ++j){
        float s0 = bf2f((unsigned short)a[2*j])   + bf2f((unsigned short)hv[2*j]);
        float s1 = bf2f((unsigned short)a[2*j+1]) + bf2f((unsigned short)hv[2*j+1]);
        o[j] = pk_bf16(s0, s1);
      }
      *(u32x4*)(hb + gof) = o;
    }
  }
}

// LDS-staged GEMM (k_in_proj / k_out only, proven, 256 thr)
template<int KCH>
__device__ __forceinline__ void gemm_64x256(const unsigned short* __restrict__ wb,
                                            char* As, char* Bs,
                                            f32x4 (&acc)[4][4], int tid)
{
  const int lane = tid & 63;
  const int c0   = (tid >> 6) * 64;
  const int lr   = lane & 15;
  const int lk16 = (lane >> 4) * 16;
  #pragma unroll
  for(int kc = 0; kc < KCH; ++kc){
    __syncthreads();
    {
      const unsigned short* src = wb + (size_t)tid * (KCH*64) + kc*64;
      #pragma unroll
      for(int i = 0; i < 8; ++i){
        short8 v = *(const short8*)(src + i*8);
        *(short8*)(Bs + swzB(tid, i*16)) = v;
      }
    }
    __syncthreads();
    #pragma unroll
    for(int t2 = 0; t2 < 2; ++t2){
      bf16x8 af[4], bfr[4];
      #pragma unroll
      for(int fr = 0; fr < 4; ++fr)
        af[fr] = *(const bf16x8*)(As + swzA(fr*16 + lr, kc*128 + t2*64 + lk16));
      #pragma unroll
      for(int fc = 0; fc < 4; ++fc)
        bfr[fc] = *(const bf16x8*)(Bs + swzB(c0 + fc*16 + lr, t2*64 + lk16));
      #pragma unroll
      for(int fr = 0; fr < 4; ++fr)
        #pragma unroll
        for(int fc = 0; fc < 4; ++fc)
          acc[fr][fc] = __builtin_amdgcn_mfma_f32_16x16x32_bf16(af[fr], bfr[fc], acc[fr][fc], 0, 0, 0);
    }
  }
}

// ---------------- prep kernels ----------------
__global__ void k_cvt(const float* __restrict__ s, unsigned short* __restrict__ d, int n){
  int i = blockIdx.x*256 + threadIdx.x;
  if(i < n) d[i] = f2bf(s[i]);
}
__global__ void k_cvt_inw(const float* __restrict__ w, unsigned short* __restrict__ d){
  int i = blockIdx.x*256 + threadIdx.x;
  int n = i >> 7, f = i & 127;
  d[i] = (f < 96) ? f2bf(w[n*96 + f]) : (unsigned short)0;
}
__global__ void k_spT(const float* __restrict__ spw, unsigned short* __restrict__ d){
  int l = blockIdx.y;
  int i = blockIdx.x*256 + threadIdx.x;
  int dd = i >> 8, ss = i & 255;
  d[l*65536 + i] = f2bf(spw[l*65536 + ss*256 + dd]);
}
__global__ void k_decay(const float* __restrict__ A_log, float* __restrict__ decay){
  __shared__ float red[4];
  const int b = blockIdx.x;
  const int tid = threadIdx.x;
  float v = expf(A_log[(size_t)b*256 + tid]);
  #pragma unroll
  for(int o = 32; o >= 1; o >>= 1) v += __shfl_xor(v, o);
  if((tid & 63) == 0) red[tid >> 6] = v;
  __syncthreads();
  if(tid == 0){
    float s = red[0] + red[1] + red[2] + red[3];
    decay[b] = expf(-s * (1.f/256.f));
  }
}

// ---------------- h = gelu(LN(x @ in_w^T + in_b)) -> bf16 (proven) ----------------
__global__ __launch_bounds__(256) void k_in_proj(
    const float* __restrict__ x_g,
    const unsigned short* __restrict__ in_wb,
    const float* __restrict__ in_b,
    const float* __restrict__ ln_gv, const float* __restrict__ ln_bv,
    unsigned short* __restrict__ h_g)
{
  __shared__ char smem[65536];
  char* As = smem; char* Bs = smem + 32768;
  const int tid = threadIdx.x;
  const int m0 = blockIdx.x * 64;
  const int lane = tid & 63, c0w = (tid>>6)*64, lr = lane & 15, rb = (lane>>4)*4;
  {
    const int r = tid >> 2, cq = tid & 3;
    const float* src = x_g + (size_t)(m0 + r)*FIN + cq*24;
    unsigned short tmp[24] __attribute__((aligned(16)));
    #pragma unroll
    for(int i = 0; i < 6; ++i){
      float4 v = *(const float4*)(src + i*4);
      tmp[4*i]=f2bf(v.x); tmp[4*i+1]=f2bf(v.y); tmp[4*i+2]=f2bf(v.z); tmp[4*i+3]=f2bf(v.w);
    }
    #pragma unroll
    for(int i = 0; i < 3; ++i)
      *(short8*)(As + swzA(r, cq*48 + i*16)) = *(const short8*)(tmp + i*8);
    if(cq == 3){
      short8 z8 = {0,0,0,0,0,0,0,0};
      #pragma unroll
      for(int i = 0; i < 4; ++i)
        *(short8*)(As + swzA(r, 192 + i*16)) = z8;
    }
  }
  f32x4 acc[4][4]; zero_acc(acc);
  gemm_64x256<2>(in_wb, As, Bs, acc, tid);
  __syncthreads();
  #pragma unroll
  for(int fc = 0; fc < 4; ++fc){
    const int col = c0w + fc*16 + lr;
    const float bb = in_b[col];
    #pragma unroll
    for(int fr = 0; fr < 4; ++fr)
      #pragma unroll
      for(int rg = 0; rg < 4; ++rg){
        const int row = fr*16 + rb + rg;
        *(float*)(smem + (((unsigned)(row*1024 + col*4)) ^ ((row&7)<<4))) = acc[fr][fc][rg] + bb;
      }
  }
  __syncthreads();
  {
    const int r = tid >> 2, c0 = (tid & 3) * 64;
    float vals[64]; float sm = 0.f, sq = 0.f;
    #pragma unroll
    for(int i = 0; i < 16; ++i){
      float4 v = *(const float4*)(smem + (((unsigned)(r*1024 + (c0 + i*4)*4)) ^ ((r&7)<<4)));
      vals[4*i]=v.x; vals[4*i+1]=v.y; vals[4*i+2]=v.z; vals[4*i+3]=v.w;
    }
    #pragma unroll
    for(int i = 0; i < 64; ++i){ sm += vals[i]; sq += vals[i]*vals[i]; }
    sm += __shfl_xor(sm, 1); sm += __shfl_xor(sm, 2);
    sq += __shfl_xor(sq, 1); sq += __shfl_xor(sq, 2);
    const float mu = sm * (1.f/256.f);
    const float rstd = rsqrtf(sq * (1.f/256.f) - mu*mu + 1e-5f);
    unsigned short* dst = h_g + (size_t)(m0 + r)*DMODEL + c0;
    #pragma unroll
    for(int i = 0; i < 8; ++i){
      float g[8];
      #pragma unroll
      for(int j = 0; j < 8; ++j){
        const int c = c0 + i*8 + j;
        g[j] = gelu_f((vals[i*8+j]-mu)*rstd*ln_gv[c] + ln_bv[c]);
      }
      u32x4 o;
      o[0] = pk_bf16(g[0],g[1]); o[1] = pk_bf16(g[2],g[3]);
      o[2] = pk_bf16(g[4],g[5]); o[3] = pk_bf16(g[6],g[7]);
      *(u32x4*)(dst + i*8) = o;
    }
  }
}

// ---------------- BOTH layers, two-tile pipelined: block = sequence, 512 thr ----------------
__global__ __launch_bounds__(512,2) void k_layers(
    unsigned short* __restrict__ h_g,
    const unsigned short* __restrict__ gate_w0,
    const unsigned short* __restrict__ sp_w0,
    const unsigned short* __restrict__ spT_w0,
    const unsigned short* __restrict__ op_w0,
    const float* __restrict__ ln_g0, const float* __restrict__ ln_b0,
    const float* __restrict__ gate_b0, const float* __restrict__ sp_b0,
    const float* __restrict__ decay0, const float* __restrict__ D0,
    const float* __restrict__ op_b0)
{
  __shared__ char As0[32768];
  __shared__ char Ss0[32768];
  __shared__ char As1[32768];
  __shared__ char Ss1[32768];
  const int tid = threadIdx.x;
  const int n = blockIdx.x;
  const int lane = tid & 63;
  const int c0w = (tid >> 6) * 32;            // wave -> 32 output cols
  const int rA = tid >> 3, cAh = (tid & 7) * 32;   // LN: 8 thr/row
  float st = 0.f;                              // scan state across layers

  #pragma unroll 1
  for(int l = 0; l < 2; ++l){
    const unsigned short* gw  = gate_w0 + l*65536;
    const unsigned short* spw = sp_w0   + l*65536;
    const unsigned short* spT = spT_w0  + l*65536;
    const unsigned short* opw = op_w0   + l*65536;
    const float* lg  = ln_g0   + l*256;
    const float* lb  = ln_b0   + l*256;
    const float* gb_ = gate_b0 + l*256;
    const float* sb_ = sp_b0   + l*256;
    const float* Dv_ = D0      + l*256;
    const float* ob_ = op_b0   + l*256;
    const float dc = decay0[l*256 + (tid & 255)];
    const int mL = n*KSEQ;

    // prologue: tile 0 front phases on buffer pair 0 (LDS deps only -> barx)
    ph_ln(h_g, mL, As0, lg, lb, rA, cAh);
    barx();
    ph_gate(gw, As0, Ss0, gb_, lane, c0w);
    barx();
    ph_sp(spw, Ss0, As0, sb_, lane, c0w);
    barx();

    #pragma unroll 1
    for(int kb = 0; kb < 8; ++kb){
      char* Ab = (kb & 1) ? As1 : As0;
      char* Sb = (kb & 1) ? Ss1 : Ss0;
      char* Af = (kb & 1) ? As0 : As1;
      char* Sf = (kb & 1) ? Ss0 : Ss1;
      const int m0 = mL + kb*64;
      // SP1: front LN (global loads stay in flight) || back scan
      if(kb < 7) ph_ln(h_g, m0 + 64, Af, lg, lb, rA, cAh);
      ph_scan(Ab, st, dc, tid);
      barx();
      // SP2: back spT + y-epi (Ss in place) || front gate + xg-epi
      ph_spt_y(spT, Ab, Sb, Dv_, lane, c0w);
      if(kb < 7) ph_gate(gw, Af, Sf, gb_, lane, c0w);
      barx();
      // SP3: back op + op-epi + h-RMW || front sp + s-epi
      ph_op_rmw(opw, Sb, Ab, ob_, h_g, m0, lane, c0w);
      if(kb < 7) ph_sp(spw, Sf, Af, sb_, lane, c0w);
      barx();
    }
    // layer boundary: full drain so h-RMW stores are visible to next layer's LN
    __syncthreads();
  }
}

// ---------------- out = gelu(LN(h[:,511,:] @ out_w^T + out_b)) (proven) ----------------
__global__ __launch_bounds__(256) void k_out(
    const unsigned short* __restrict__ h_g,
    const unsigned short* __restrict__ out_wb,
    const float* __restrict__ out_bv,
    const float* __restrict__ ln_gv, const float* __restrict__ ln_bv,
    float* __restrict__ out_g)
{
  __shared__ char smem[65536];
  char* As = smem; char* Bs = smem + 32768;
  const int tid = threadIdx.x;
  const int r0 = blockIdx.x * 64;
  const int lane = tid & 63, c0w = (tid>>6)*64, lr = lane & 15, rb = (lane>>4)*4;
  {
    const int r = tid >> 2, c0 = (tid & 3) * 64;
    const unsigned short* src = h_g + ((size_t)(r0 + r)*KSEQ + (KSEQ-1))*DMODEL + c0;
    #pragma unroll
    for(int i = 0; i < 8; ++i){
      short8 v = *(const short8*)(src + i*8);
      *(short8*)(As + swzA(r, c0*2 + i*16)) = v;
    }
  }
  f32x4 acc[4][4]; zero_acc(acc);
  gemm_64x256<4>(out_wb, As, Bs, acc, tid);
  __syncthreads();
  #pragma unroll
  for(int fc = 0; fc < 4; ++fc){
    const int col = c0w + fc*16 + lr;
    const float bb = out_bv[col];
    #pragma unroll
    for(int fr = 0; fr < 4; ++fr)
      #pragma unroll
      for(int rg = 0; rg < 4; ++rg){
        const int row = fr*16 + rb + rg;
        *(float*)(smem + (((unsigned)(row*1024 + col*4)) ^ ((row&7)<<4))) = acc[fr][fc][rg] + bb;
      }
  }
  __syncthreads();
  {
    const int r = tid >> 2, c0 = (tid & 3) * 64;
    float vals[64]; float sm = 0.f, sq = 0.f;
    #pragma unroll
    for(int i = 0; i < 16; ++i){
      float4 v = *(const float4*)(smem + (((unsigned)(r*1024 + (c0 + i*4)*4)) ^ ((r&7)<<4)));
      vals[4*i]=v.x; vals[4*i+1]=v.y; vals[4*i+2]=v.z; vals[4*i+3]=v.w;
    }
    #pragma unroll
    for(int i = 0; i < 64; ++i){ sm += vals[i]; sq += vals[i]*vals[i]; }
    sm += __shfl_xor(sm, 1); sm += __shfl_xor(sm, 2);
    sq += __shfl_xor(sq, 1); sq += __shfl_xor(sq, 2);
    const float mu = sm * (1.f/256.f);
    const float rstd = rsqrtf(sq * (1.f/256.f) - mu*mu + 1e-5f);
    float* dst = out_g + (size_t)(r0 + r)*DMODEL + c0;
    #pragma unroll
    for(int i = 0; i < 16; ++i){
      float4 o;
      o.x = gelu_f((vals[4*i+0]-mu)*rstd*ln_gv[c0+i*4+0] + ln_bv[c0+i*4+0]);
      o.y = gelu_f((vals[4*i+1]-mu)*rstd*ln_gv[c0+i*4+1] + ln_bv[c0+i*4+1]);
      o.z = gelu_f((vals[4*i+2]-mu)*rstd*ln_gv[c0+i*4+2] + ln_bv[c0+i*4+2]);
      o.w = gelu_f((vals[4*i+3]-mu)*rstd*ln_gv[c0+i*4+3] + ln_bv[c0+i*4+3]);
      *(float4*)(dst + i*4) = o;
    }
  }
}

extern "C" void kernel_launch(void* const* d_in, const int* in_sizes, int n_in,
                              void* d_out, int out_size, void* d_ws, size_t ws_size,
                              hipStream_t stream) {
  (void)in_sizes; (void)n_in; (void)out_size; (void)ws_size;
  const float* x        = (const float*)d_in[0];
  const float* in_w     = (const float*)d_in[1];
  const float* in_b     = (const float*)d_in[2];
  const float* in_ln_g  = (const float*)d_in[3];
  const float* in_ln_b  = (const float*)d_in[4];
  const float* ln_g     = (const float*)d_in[5];
  const float* ln_b     = (const float*)d_in[6];
  const float* gate_w   = (const float*)d_in[7];
  const float* gate_b   = (const float*)d_in[8];
  const float* sp_w     = (const float*)d_in[9];
  const float* sp_b     = (const float*)d_in[10];
  const float* op_w     = (const float*)d_in[11];
  const float* op_b     = (const float*)d_in[12];
  const float* A_log    = (const float*)d_in[13];
  const float* Dp       = (const float*)d_in[14];
  const float* out_w    = (const float*)d_in[15];
  const float* out_b    = (const float*)d_in[16];
  const float* out_ln_g = (const float*)d_in[17];
  const float* out_ln_b = (const float*)d_in[18];

  char* ws = (char*)d_ws;
  // ~133.7 MiB workspace (proven budget)
  unsigned short* h_g       = (unsigned short*)(ws + 0);           // 128 MiB
  float*          decay     = (float*)(ws + 134217728);            // 2 KiB
  unsigned short* wbase     = (unsigned short*)(ws + 134219776);   // ~1.2 MiB
  unsigned short* in_wb  = wbase;               // 32768
  unsigned short* gate_wb= in_wb  + 32768;      // 2*65536
  unsigned short* sp_wb  = gate_wb+ 131072;
  unsigned short* sp_wTb = sp_wb  + 131072;
  unsigned short* op_wb  = sp_wTb + 131072;
  unsigned short* out_wb = op_wb  + 131072;     // 65536

  // prep
  k_cvt_inw<<<128, 256, 0, stream>>>(in_w, in_wb);
  k_cvt<<<512, 256, 0, stream>>>(gate_w, gate_wb, 131072);
  k_cvt<<<512, 256, 0, stream>>>(sp_w,   sp_wb,   131072);
  k_cvt<<<512, 256, 0, stream>>>(op_w,   op_wb,   131072);
  k_cvt<<<256, 256, 0, stream>>>(out_w,  out_wb,  65536);
  k_spT<<<dim3(256,2), 256, 0, stream>>>(sp_w, sp_wTb);
  k_decay<<<512, 256, 0, stream>>>(A_log, decay);

  // pipeline
  k_in_proj<<<MTOT/64, 256, 0, stream>>>(x, in_wb, in_b, in_ln_g, in_ln_b, h_g);
  k_layers<<<NSEQ, 512, 0, stream>>>(h_g, gate_wb, sp_wb, sp_wTb, op_wb,
      ln_g, ln_b, gate_b, sp_b, decay, Dp, op_b);
  k_out<<<NSEQ/64, 256, 0, stream>>>(h_g, out_wb, out_b, out_ln_g, out_ln_b, (float*)d_out);
}

// Round 18
// 945.880 us; speedup vs baseline: 1.4520x; 1.0211x over previous
//
#include <hip/hip_runtime.h>
#include <hip/hip_bf16.h>

// MambaEncoder on MI355X — v18: v16/17 base (966us) + final latency fixes:
//  (1) T14 early-issue of h_old RMW loads BEFORE the op GEMM in SP3
//  (2) SP1 wave-split: waves 0-3 scan(k) (they own the channels), waves 4-7
//      do LN(k+1) -> SP1 critical path = max(scan, LN) not LN-then-scan.
// Bit-identical numerics. ws ~133.7MiB.

typedef __attribute__((ext_vector_type(8))) __bf16 bf16x8;
typedef __attribute__((ext_vector_type(8))) short short8;
typedef __attribute__((ext_vector_type(4))) float f32x4;
typedef __attribute__((ext_vector_type(4))) unsigned u32x4;
typedef __attribute__((ext_vector_type(2))) unsigned u32x2;

#define NSEQ 512
#define KSEQ 512
#define FIN 96
#define DMODEL 256
#define MTOT (NSEQ*KSEQ)

__device__ __forceinline__ unsigned short f2bf(float f){
  union { float f; unsigned u; } v; v.f = f;
  unsigned r = (v.u + 0x7FFFu + ((v.u >> 16) & 1u)) >> 16;
  return (unsigned short)r;
}
__device__ __forceinline__ float bf2f(unsigned short b){
  union { unsigned u; float f; } v; v.u = ((unsigned)b) << 16; return v.f;
}
__device__ __forceinline__ unsigned pk_bf16(float lo, float hi){
  unsigned r;
  asm("v_cvt_pk_bf16_f32 %0, %1, %2" : "=v"(r) : "v"(lo), "v"(hi));
  return r;
}
__device__ __forceinline__ float gelu_f(float x){
  return 0.5f * x * (1.0f + erff(x * 0.70710678118654752440f));
}
__device__ __forceinline__ float silu_f(float x){
  return x / (1.0f + __expf(-x));
}
__device__ __forceinline__ unsigned swzA(int row, int kbyte){   // [64][256] bf16, 512B stride
  return ((unsigned)(row*512 + kbyte)) ^ (unsigned)((row & 7) << 4);
}
__device__ __forceinline__ unsigned swzB(int n, int kbyte){     // [256][64] bf16
  return ((unsigned)(n*128 + kbyte)) ^ (unsigned)((n & 7) << 4);
}

// 8-wave col-split GEMM, operand-swapped (v16): acc[fr][fc][reg] ->
//   actrow = fr*16 + (lane&15), wcol = c0 + fc*16 + (lane>>4)*4 + reg.
__device__ __forceinline__ void gemm_w8(const unsigned short* __restrict__ wb,
                                        const char* As, f32x4 (&acc)[4][2],
                                        int lane, int c0)
{
  const int lr  = lane & 15;
  const int lk8 = (lane >> 4) * 8;
  const unsigned short* bp = wb + (size_t)(c0 + lr)*256 + lk8;   // +fc*4096 +kc*32
  bf16x8 bb[4][2];
  #pragma unroll
  for(int p = 0; p < 4; ++p)
    #pragma unroll
    for(int fc = 0; fc < 2; ++fc)
      bb[p][fc] = *(const bf16x8*)(bp + fc*4096 + p*32);
  #pragma unroll
  for(int kc = 0; kc < 8; ++kc){
    bf16x8 af[4];
    #pragma unroll
    for(int fr = 0; fr < 4; ++fr)
      af[fr] = *(const bf16x8*)(As + swzA(fr*16 + lr, kc*64 + lk8*2));
    #pragma unroll
    for(int fr = 0; fr < 4; ++fr)
      #pragma unroll
      for(int fc = 0; fc < 2; ++fc)
        acc[fr][fc] = __builtin_amdgcn_mfma_f32_16x16x32_bf16(bb[kc&3][fc], af[fr], acc[fr][fc], 0, 0, 0);
    if(kc < 4){
      #pragma unroll
      for(int fc = 0; fc < 2; ++fc)
        bb[kc&3][fc] = *(const bf16x8*)(bp + fc*4096 + (kc+4)*32);
    }
  }
}

__device__ __forceinline__ void zero_acc2(f32x4 (&acc)[4][2]){
  #pragma unroll
  for(int a=0;a<4;++a)
    #pragma unroll
    for(int b=0;b<2;++b)
      acc[a][b] = (f32x4){0.f,0.f,0.f,0.f};
}
__device__ __forceinline__ void zero_acc(f32x4 (&acc)[4][4]){
  #pragma unroll
  for(int a=0;a<4;++a)
    #pragma unroll
    for(int b=0;b<4;++b)
      acc[a][b] = (f32x4){0.f,0.f,0.f,0.f};
}

// ---------------- k_layers phase helpers ----------------
// LN over a 32-row half (rows hrow0..hrow0+31) using one 4-wave group (256 thr):
// 8 thr/row mapping within the group.
__device__ __forceinline__ void ph_ln_half(const unsigned short* __restrict__ h_g, int m0,
    char* A, const float* __restrict__ lg, const float* __restrict__ lb,
    int gtid /*0..255*/, int hrow0)
{
  const int rA = hrow0 + (gtid >> 3);
  const int cAh = (gtid & 7) * 32;
  const unsigned short* src = h_g + (size_t)(m0 + rA)*DMODEL + cAh;
  short8 hv[4];
  #pragma unroll
  for(int i = 0; i < 4; ++i) hv[i] = *(const short8*)(src + i*8);
  float sm = 0.f, sq = 0.f;
  #pragma unroll
  for(int i = 0; i < 4; ++i)
    #pragma unroll
    for(int j = 0; j < 8; ++j){
      float v = bf2f((unsigned short)hv[i][j]); sm += v; sq += v*v;
    }
  sm += __shfl_xor(sm, 1); sm += __shfl_xor(sm, 2); sm += __shfl_xor(sm, 4);
  sq += __shfl_xor(sq, 1); sq += __shfl_xor(sq, 2); sq += __shfl_xor(sq, 4);
  const float mu = sm * (1.f/256.f);
  const float rstd = rsqrtf(sq * (1.f/256.f) - mu*mu + 1e-5f);
  #pragma unroll
  for(int i = 0; i < 4; ++i){
    float z[8];
    #pragma unroll
    for(int j = 0; j < 8; ++j){
      const int c = cAh + i*8 + j;
      z[j] = (bf2f((unsigned short)hv[i][j])-mu)*rstd*lg[c] + lb[c];
    }
    u32x4 zz;
    zz[0] = pk_bf16(z[0],z[1]); zz[1] = pk_bf16(z[2],z[3]);
    zz[2] = pk_bf16(z[4],z[5]); zz[3] = pk_bf16(z[6],z[7]);
    *(u32x4*)(A + swzA(rA, cAh*2 + i*16)) = zz;
  }
}

__device__ __forceinline__ void ph_gate(const unsigned short* __restrict__ gw,
    const char* A, char* S, const float* __restrict__ gb_,
    int lane, int c0w)
{
  f32x4 acc[4][2]; zero_acc2(acc);
  gemm_w8(gw, A, acc, lane, c0w);
  const int nrow = lane & 15;
  const int mc4  = (lane >> 4) * 4;
  #pragma unroll
  for(int fc = 0; fc < 2; ++fc){
    const int colb = c0w + fc*16 + mc4;
    const f32x4 gb4 = *(const f32x4*)(gb_ + colb);
    #pragma unroll
    for(int fr = 0; fr < 4; ++fr){
      const int row = fr*16 + nrow;
      float v0 = silu_f(acc[fr][fc][0] + gb4[0]), v1 = silu_f(acc[fr][fc][1] + gb4[1]);
      float v2 = silu_f(acc[fr][fc][2] + gb4[2]), v3 = silu_f(acc[fr][fc][3] + gb4[3]);
      u32x2 w; w[0] = pk_bf16(v0, v1); w[1] = pk_bf16(v2, v3);
      *(u32x2*)(S + swzA(row, colb*2)) = w;
    }
  }
}

__device__ __forceinline__ void ph_sp(const unsigned short* __restrict__ spw,
    const char* S, char* A, const float* __restrict__ sb_,
    int lane, int c0w)
{
  f32x4 acc[4][2]; zero_acc2(acc);
  gemm_w8(spw, S, acc, lane, c0w);
  const int nrow = lane & 15;
  const int mc4  = (lane >> 4) * 4;
  #pragma unroll
  for(int fc = 0; fc < 2; ++fc){
    const int colb = c0w + fc*16 + mc4;
    const f32x4 sb4 = *(const f32x4*)(sb_ + colb);
    #pragma unroll
    for(int fr = 0; fr < 4; ++fr){
      const int row = fr*16 + nrow;
      u32x2 w;
      w[0] = pk_bf16(acc[fr][fc][0] + sb4[0], acc[fr][fc][1] + sb4[1]);
      w[1] = pk_bf16(acc[fr][fc][2] + sb4[2], acc[fr][fc][3] + sb4[3]);
      *(u32x2*)(A + swzA(row, colb*2)) = w;
    }
  }
}

// scan in A (thread=channel, gtid 0..255 of waves 0-3), chunked 16
__device__ __forceinline__ void ph_scan(char* A, float& st, float dc, int ch)
{
  #pragma unroll
  for(int c4 = 0; c4 < 4; ++c4){
    const int base = c4*16;
    float v[16];
    #pragma unroll
    for(int j = 0; j < 16; ++j)
      v[j] = bf2f(*(const unsigned short*)(A + swzA(base+j, ch*2)));
    #pragma unroll
    for(int j = 0; j < 16; ++j){ st = st*dc + v[j]; v[j] = st; }
    #pragma unroll
    for(int j = 0; j < 8; ++j){
      unsigned p = pk_bf16(v[2*j], v[2*j+1]);
      *(unsigned short*)(A + swzA(base+2*j,   ch*2)) = (unsigned short)p;
      *(unsigned short*)(A + swzA(base+2*j+1, ch*2)) = (unsigned short)(p >> 16);
    }
  }
}

__device__ __forceinline__ void ph_spt_y(const unsigned short* __restrict__ spT,
    const char* A, char* S, const float* __restrict__ Dv_,
    int lane, int c0w)
{
  f32x4 acc[4][2]; zero_acc2(acc);
  gemm_w8(spT, A, acc, lane, c0w);
  const int nrow = lane & 15;
  const int mc4  = (lane >> 4) * 4;
  #pragma unroll
  for(int fc = 0; fc < 2; ++fc){
    const int colb = c0w + fc*16 + mc4;
    const f32x4 D4 = *(const f32x4*)(Dv_ + colb);
    #pragma unroll
    for(int fr = 0; fr < 4; ++fr){
      const int row = fr*16 + nrow;
      const unsigned a = swzA(row, colb*2);
      u32x2 xg = *(const u32x2*)(S + a);
      float y0 = acc[fr][fc][0] + D4[0]*bf2f((unsigned short)xg[0]);
      float y1 = acc[fr][fc][1] + D4[1]*bf2f((unsigned short)(xg[0] >> 16));
      float y2 = acc[fr][fc][2] + D4[2]*bf2f((unsigned short)xg[1]);
      float y3 = acc[fr][fc][3] + D4[3]*bf2f((unsigned short)(xg[1] >> 16));
      u32x2 w; w[0] = pk_bf16(y0, y1); w[1] = pk_bf16(y2, y3);
      *(u32x2*)(S + a) = w;
    }
  }
}

// op GEMM(S=y) with EARLY-ISSUED h_old loads (T14): h reads hide under GEMM.
__device__ __forceinline__ void ph_op_rmw(const unsigned short* __restrict__ opw,
    const char* S, char* A, const float* __restrict__ ob_,
    unsigned short* __restrict__ h_g, int m0,
    int lane, int c0w)
{
  // early-issue h_old (own 32 cols, 64B sector chunks per row)
  char* hb = (char*)(h_g + (size_t)m0*DMODEL);
  const int cl = lane & 3;
  const int rbase = lane >> 2;
  short8 hold[4];
  #pragma unroll
  for(int p = 0; p < 4; ++p){
    const int row = p*16 + rbase;
    hold[p] = *(const short8*)(hb + (unsigned)(row*512 + c0w*2 + cl*16));
  }
  f32x4 acc[4][2]; zero_acc2(acc);
  gemm_w8(opw, S, acc, lane, c0w);
  const int nrow = lane & 15;
  const int mc4  = (lane >> 4) * 4;
  #pragma unroll
  for(int fc = 0; fc < 2; ++fc){
    const int colb = c0w + fc*16 + mc4;
    const f32x4 ob4 = *(const f32x4*)(ob_ + colb);
    #pragma unroll
    for(int fr = 0; fr < 4; ++fr){
      const int row = fr*16 + nrow;
      u32x2 w;
      w[0] = pk_bf16(acc[fr][fc][0] + ob4[0], acc[fr][fc][1] + ob4[1]);
      w[1] = pk_bf16(acc[fr][fc][2] + ob4[2], acc[fr][fc][3] + ob4[3]);
      *(u32x2*)(A + swzA(row, colb*2)) = w;
    }
  }
  // RMW using pre-loaded h_old; A op-epi values read back (same wave, own cols)
  #pragma unroll
  for(int p = 0; p < 4; ++p){
    const int row = p*16 + rbase;
    const unsigned gof = (unsigned)(row*512 + c0w*2 + cl*16);
    short8 a = *(const short8*)(A + swzA(row, c0w*2 + cl*16));
    short8 h8 = hold[p];
    u32x4 o;
    #pragma unroll
    for(int j = 0; j < 4; ++j){
      float s0 = bf2f((unsigned short)a[2*j])   + bf2f((unsigned short)h8[2*j]);
      float s1 = bf2f((unsigned short)a[2*j+1]) + bf2f((unsigned short)h8[2*j+1]);
      o[j] = pk_bf16(s0, s1);
    }
    *(u32x4*)(hb + gof) = o;
  }
}

// LDS-staged GEMM (k_in_proj / k_out only, proven, 256 thr)
template<int KCH>
__device__ __forceinline__ void gemm_64x256(const unsigned short* __restrict__ wb,
                                            char* As, char* Bs,
                                            f32x4 (&acc)[4][4], int tid)
{
  const int lane = tid & 63;
  const int c0   = (tid >> 6) * 64;
  const int lr   = lane & 15;
  const int lk16 = (lane >> 4) * 16;
  #pragma unroll
  for(int kc = 0; kc < KCH; ++kc){
    __syncthreads();
    {
      const unsigned short* src = wb + (size_t)tid * (KCH*64) + kc*64;
      #pragma unroll
      for(int i = 0; i < 8; ++i){
        short8 v = *(const short8*)(src + i*8);
        *(short8*)(Bs + swzB(tid, i*16)) = v;
      }
    }
    __syncthreads();
    #pragma unroll
    for(int t2 = 0; t2 < 2; ++t2){
      bf16x8 af[4], bfr[4];
      #pragma unroll
      for(int fr = 0; fr < 4; ++fr)
        af[fr] = *(const bf16x8*)(As + swzA(fr*16 + lr, kc*128 + t2*64 + lk16));
      #pragma unroll
      for(int fc = 0; fc < 4; ++fc)
        bfr[fc] = *(const bf16x8*)(Bs + swzB(c0 + fc*16 + lr, t2*64 + lk16));
      #pragma unroll
      for(int fr = 0; fr < 4; ++fr)
        #pragma unroll
        for(int fc = 0; fc < 4; ++fc)
          acc[fr][fc] = __builtin_amdgcn_mfma_f32_16x16x32_bf16(af[fr], bfr[fc], acc[fr][fc], 0, 0, 0);
    }
  }
}

// ---------------- prep kernels ----------------
__global__ void k_cvt(const float* __restrict__ s, unsigned short* __restrict__ d, int n){
  int i = blockIdx.x*256 + threadIdx.x;
  if(i < n) d[i] = f2bf(s[i]);
}
__global__ void k_cvt_inw(const float* __restrict__ w, unsigned short* __restrict__ d){
  int i = blockIdx.x*256 + threadIdx.x;
  int n = i >> 7, f = i & 127;
  d[i] = (f < 96) ? f2bf(w[n*96 + f]) : (unsigned short)0;
}
__global__ void k_spT(const float* __restrict__ spw, unsigned short* __restrict__ d){
  int l = blockIdx.y;
  int i = blockIdx.x*256 + threadIdx.x;
  int dd = i >> 8, ss = i & 255;
  d[l*65536 + i] = f2bf(spw[l*65536 + ss*256 + dd]);
}
__global__ void k_decay(const float* __restrict__ A_log, float* __restrict__ decay){
  __shared__ float red[4];
  const int b = blockIdx.x;
  const int tid = threadIdx.x;
  float v = expf(A_log[(size_t)b*256 + tid]);
  #pragma unroll
  for(int o = 32; o >= 1; o >>= 1) v += __shfl_xor(v, o);
  if((tid & 63) == 0) red[tid >> 6] = v;
  __syncthreads();
  if(tid == 0){
    float s = red[0] + red[1] + red[2] + red[3];
    decay[b] = expf(-s * (1.f/256.f));
  }
}

// ---------------- h = gelu(LN(x @ in_w^T + in_b)) -> bf16 (proven) ----------------
__global__ __launch_bounds__(256) void k_in_proj(
    const float* __restrict__ x_g,
    const unsigned short* __restrict__ in_wb,
    const float* __restrict__ in_b,
    const float* __restrict__ ln_gv, const float* __restrict__ ln_bv,
    unsigned short* __restrict__ h_g)
{
  __shared__ char smem[65536];
  char* As = smem; char* Bs = smem + 32768;
  const int tid = threadIdx.x;
  const int m0 = blockIdx.x * 64;
  const int lane = tid & 63, c0w = (tid>>6)*64, lr = lane & 15, rb = (lane>>4)*4;
  {
    const int r = tid >> 2, cq = tid & 3;
    const float* src = x_g + (size_t)(m0 + r)*FIN + cq*24;
    unsigned short tmp[24] __attribute__((aligned(16)));
    #pragma unroll
    for(int i = 0; i < 6; ++i){
      float4 v = *(const float4*)(src + i*4);
      tmp[4*i]=f2bf(v.x); tmp[4*i+1]=f2bf(v.y); tmp[4*i+2]=f2bf(v.z); tmp[4*i+3]=f2bf(v.w);
    }
    #pragma unroll
    for(int i = 0; i < 3; ++i)
      *(short8*)(As + swzA(r, cq*48 + i*16)) = *(const short8*)(tmp + i*8);
    if(cq == 3){
      short8 z8 = {0,0,0,0,0,0,0,0};
      #pragma unroll
      for(int i = 0; i < 4; ++i)
        *(short8*)(As + swzA(r, 192 + i*16)) = z8;
    }
  }
  f32x4 acc[4][4]; zero_acc(acc);
  gemm_64x256<2>(in_wb, As, Bs, acc, tid);
  __syncthreads();
  #pragma unroll
  for(int fc = 0; fc < 4; ++fc){
    const int col = c0w + fc*16 + lr;
    const float bb = in_b[col];
    #pragma unroll
    for(int fr = 0; fr < 4; ++fr)
      #pragma unroll
      for(int rg = 0; rg < 4; ++rg){
        const int row = fr*16 + rb + rg;
        *(float*)(smem + (((unsigned)(row*1024 + col*4)) ^ ((row&7)<<4))) = acc[fr][fc][rg] + bb;
      }
  }
  __syncthreads();
  {
    const int r = tid >> 2, c0 = (tid & 3) * 64;
    float vals[64]; float sm = 0.f, sq = 0.f;
    #pragma unroll
    for(int i = 0; i < 16; ++i){
      float4 v = *(const float4*)(smem + (((unsigned)(r*1024 + (c0 + i*4)*4)) ^ ((r&7)<<4)));
      vals[4*i]=v.x; vals[4*i+1]=v.y; vals[4*i+2]=v.z; vals[4*i+3]=v.w;
    }
    #pragma unroll
    for(int i = 0; i < 64; ++i){ sm += vals[i]; sq += vals[i]*vals[i]; }
    sm += __shfl_xor(sm, 1); sm += __shfl_xor(sm, 2);
    sq += __shfl_xor(sq, 1); sq += __shfl_xor(sq, 2);
    const float mu = sm * (1.f/256.f);
    const float rstd = rsqrtf(sq * (1.f/256.f) - mu*mu + 1e-5f);
    unsigned short* dst = h_g + (size_t)(m0 + r)*DMODEL + c0;
    #pragma unroll
    for(int i = 0; i < 8; ++i){
      float g[8];
      #pragma unroll
      for(int j = 0; j < 8; ++j){
        const int c = c0 + i*8 + j;
        g[j] = gelu_f((vals[i*8+j]-mu)*rstd*ln_gv[c] + ln_bv[c]);
      }
      u32x4 o;
      o[0] = pk_bf16(g[0],g[1]); o[1] = pk_bf16(g[2],g[3]);
      o[2] = pk_bf16(g[4],g[5]); o[3] = pk_bf16(g[6],g[7]);
      *(u32x4*)(dst + i*8) = o;
    }
  }
}

// ---------------- BOTH layers, two-tile pipelined: block = sequence, 512 thr ----------------
__global__ __launch_bounds__(512,2) void k_layers(
    unsigned short* __restrict__ h_g,
    const unsigned short* __restrict__ gate_w0,
    const unsigned short* __restrict__ sp_w0,
    const unsigned short* __restrict__ spT_w0,
    const unsigned short* __restrict__ op_w0,
    const float* __restrict__ ln_g0, const float* __restrict__ ln_b0,
    const float* __restrict__ gate_b0, const float* __restrict__ sp_b0,
    const float* __restrict__ decay0, const float* __restrict__ D0,
    const float* __restrict__ op_b0)
{
  __shared__ char As0[32768];
  __shared__ char Ss0[32768];
  __shared__ char As1[32768];
  __shared__ char Ss1[32768];
  const int tid = threadIdx.x;
  const int n = blockIdx.x;
  const int lane = tid & 63;
  const int c0w = (tid >> 6) * 32;            // wave -> 32 output cols
  const int gtid = tid & 255;                 // 4-wave group-local id
  const int half = tid >> 8;                  // 0: waves 0-3 (scan), 1: waves 4-7 (LN k+1)
  float st = 0.f;                              // scan state across layers (half 0 only)

  #pragma unroll 1
  for(int l = 0; l < 2; ++l){
    const unsigned short* gw  = gate_w0 + l*65536;
    const unsigned short* spw = sp_w0   + l*65536;
    const unsigned short* spT = spT_w0  + l*65536;
    const unsigned short* opw = op_w0   + l*65536;
    const float* lg  = ln_g0   + l*256;
    const float* lb  = ln_b0   + l*256;
    const float* gb_ = gate_b0 + l*256;
    const float* sb_ = sp_b0   + l*256;
    const float* Dv_ = D0      + l*256;
    const float* ob_ = op_b0   + l*256;
    const float dc = decay0[l*256 + gtid];
    const int mL = n*KSEQ;

    // prologue: tile 0 front phases on buffer pair 0 (both halves do LN halves)
    ph_ln_half(h_g, mL, As0, lg, lb, gtid, half*32);
    __syncthreads();
    ph_gate(gw, As0, Ss0, gb_, lane, c0w);
    __syncthreads();
    ph_sp(spw, Ss0, As0, sb_, lane, c0w);
    __syncthreads();

    #pragma unroll 1
    for(int kb = 0; kb < 8; ++kb){
      char* Ab = (kb & 1) ? As1 : As0;
      char* Sb = (kb & 1) ? Ss1 : Ss0;
      char* Af = (kb & 1) ? As0 : As1;
      char* Sf = (kb & 1) ? Ss0 : Ss1;
      const int m0 = mL + kb*64;
      // SP1: half 0 = scan(k); half 1 = full LN(k+1) (both 32-row halves)
      if(half == 0){
        ph_scan(Ab, st, dc, gtid);
      } else if(kb < 7){
        ph_ln_half(h_g, m0 + 64, Af, lg, lb, gtid, 0);
        ph_ln_half(h_g, m0 + 64, Af, lg, lb, gtid, 32);
      }
      __syncthreads();
      // SP2: back spT + y-epi (Ss in place) || front gate + xg-epi
      ph_spt_y(spT, Ab, Sb, Dv_, lane, c0w);
      if(kb < 7) ph_gate(gw, Af, Sf, gb_, lane, c0w);
      __syncthreads();
      // SP3: back op(+early h_old)+op-epi+RMW || front sp + s-epi
      ph_op_rmw(opw, Sb, Ab, ob_, h_g, m0, lane, c0w);
      if(kb < 7) ph_sp(spw, Sf, Af, sb_, lane, c0w);
      __syncthreads();
    }
  }
}

// ---------------- out = gelu(LN(h[:,511,:] @ out_w^T + out_b)) (proven) ----------------
__global__ __launch_bounds__(256) void k_out(
    const unsigned short* __restrict__ h_g,
    const unsigned short* __restrict__ out_wb,
    const float* __restrict__ out_bv,
    const float* __restrict__ ln_gv, const float* __restrict__ ln_bv,
    float* __restrict__ out_g)
{
  __shared__ char smem[65536];
  char* As = smem; char* Bs = smem + 32768;
  const int tid = threadIdx.x;
  const int r0 = blockIdx.x * 64;
  const int lane = tid & 63, c0w = (tid>>6)*64, lr = lane & 15, rb = (lane>>4)*4;
  {
    const int r = tid >> 2, c0 = (tid & 3) * 64;
    const unsigned short* src = h_g + ((size_t)(r0 + r)*KSEQ + (KSEQ-1))*DMODEL + c0;
    #pragma unroll
    for(int i = 0; i < 8; ++i){
      short8 v = *(const short8*)(src + i*8);
      *(short8*)(As + swzA(r, c0*2 + i*16)) = v;
    }
  }
  f32x4 acc[4][4]; zero_acc(acc);
  gemm_64x256<4>(out_wb, As, Bs, acc, tid);
  __syncthreads();
  #pragma unroll
  for(int fc = 0; fc < 4; ++fc){
    const int col = c0w + fc*16 + lr;
    const float bb = out_bv[col];
    #pragma unroll
    for(int fr = 0; fr < 4; ++fr)
      #pragma unroll
      for(int rg = 0; rg < 4; ++rg){
        const int row = fr*16 + rb + rg;
        *(float*)(smem + (((unsigned)(row*1024 + col*4)) ^ ((row&7)<<4))) = acc[fr][fc][rg] + bb;
      }
  }
  __syncthreads();
  {
    const int r = tid >> 2, c0 = (tid & 3) * 64;
    float vals[64]; float sm = 0.f, sq = 0.f;
    #pragma unroll
    for(int i = 0; i < 16; ++i){
      float4 v = *(const float4*)(smem + (((unsigned)(r*1024 + (c0 + i*4)*4)) ^ ((r&7)<<4)));
      vals[4*i]=v.x; vals[4*i+1]=v.y; vals[4*i+2]=v.z; vals[4*i+3]=v.w;
    }
    #pragma unroll
    for(int i = 0; i < 64; ++i){ sm += vals[i]; sq += vals[i]*vals[i]; }
    sm += __shfl_xor(sm, 1); sm += __shfl_xor(sm, 2);
    sq += __shfl_xor(sq, 1); sq += __shfl_xor(sq, 2);
    const float mu = sm * (1.f/256.f);
    const float rstd = rsqrtf(sq * (1.f/256.f) - mu*mu + 1e-5f);
    float* dst = out_g + (size_t)(r0 + r)*DMODEL + c0;
    #pragma unroll
    for(int i = 0; i < 16; ++i){
      float4 o;
      o.x = gelu_f((vals[4*i+0]-mu)*rstd*ln_gv[c0+i*4+0] + ln_bv[c0+i*4+0]);
      o.y = gelu_f((vals[4*i+1]-mu)*rstd*ln_gv[c0+i*4+1] + ln_bv[c0+i*4+1]);
      o.z = gelu_f((vals[4*i+2]-mu)*rstd*ln_gv[c0+i*4+2] + ln_bv[c0+i*4+2]);
      o.w = gelu_f((vals[4*i+3]-mu)*rstd*ln_gv[c0+i*4+3] + ln_bv[c0+i*4+3]);
      *(float4*)(dst + i*4) = o;
    }
  }
}

extern "C" void kernel_launch(void* const* d_in, const int* in_sizes, int n_in,
                              void* d_out, int out_size, void* d_ws, size_t ws_size,
                              hipStream_t stream) {
  (void)in_sizes; (void)n_in; (void)out_size; (void)ws_size;
  const float* x        = (const float*)d_in[0];
  const float* in_w     = (const float*)d_in[1];
  const float* in_b     = (const float*)d_in[2];
  const float* in_ln_g  = (const float*)d_in[3];
  const float* in_ln_b  = (const float*)d_in[4];
  const float* ln_g     = (const float*)d_in[5];
  const float* ln_b     = (const float*)d_in[6];
  const float* gate_w   = (const float*)d_in[7];
  const float* gate_b   = (const float*)d_in[8];
  const float* sp_w     = (const float*)d_in[9];
  const float* sp_b     = (const float*)d_in[10];
  const float* op_w     = (const float*)d_in[11];
  const float* op_b     = (const float*)d_in[12];
  const float* A_log    = (const float*)d_in[13];
  const float* Dp       = (const float*)d_in[14];
  const float* out_w    = (const float*)d_in[15];
  const float* out_b    = (const float*)d_in[16];
  const float* out_ln_g = (const float*)d_in[17];
  const float* out_ln_b = (const float*)d_in[18];

  char* ws = (char*)d_ws;
  // ~133.7 MiB workspace (proven budget)
  unsigned short* h_g       = (unsigned short*)(ws + 0);           // 128 MiB
  float*          decay     = (float*)(ws + 134217728);            // 2 KiB
  unsigned short* wbase     = (unsigned short*)(ws + 134219776);   // ~1.2 MiB
  unsigned short* in_wb  = wbase;               // 32768
  unsigned short* gate_wb= in_wb  + 32768;      // 2*65536
  unsigned short* sp_wb  = gate_wb+ 131072;
  unsigned short* sp_wTb = sp_wb  + 131072;
  unsigned short* op_wb  = sp_wTb + 131072;
  unsigned short* out_wb = op_wb  + 131072;     // 65536

  // prep
  k_cvt_inw<<<128, 256, 0, stream>>>(in_w, in_wb);
  k_cvt<<<512, 256, 0, stream>>>(gate_w, gate_wb, 131072);
  k_cvt<<<512, 256, 0, stream>>>(sp_w,   sp_wb,   131072);
  k_cvt<<<512, 256, 0, stream>>>(op_w,   op_wb,   131072);
  k_cvt<<<256, 256, 0, stream>>>(out_w,  out_wb,  65536);
  k_spT<<<dim3(256,2), 256, 0, stream>>>(sp_w, sp_wTb);
  k_decay<<<512, 256, 0, stream>>>(A_log, decay);

  // pipeline
  k_in_proj<<<MTOT/64, 256, 0, stream>>>(x, in_wb, in_b, in_ln_g, in_ln_b, h_g);
  k_layers<<<NSEQ, 512, 0, stream>>>(h_g, gate_wb, sp_wb, sp_wTb, op_wb,
      ln_g, ln_b, gate_b, sp_b, decay, Dp, op_b);
  k_out<<<NSEQ/64, 256, 0, stream>>>(h_g, out_wb, out_b, out_ln_g, out_ln_b, (float*)d_out);
}